// Round 1
// baseline (528.215 us; speedup 1.0000x reference)
//
#include <hip/hip_runtime.h>
#include <math.h>

// Problem constants (reference: N=20000, E=160000, F=128, H=4, C1=128, C2=256, G=64, NCLS=10)
#define FDIM 128
#define HEADS 4
#define C1DIM 128
#define C2DIM 256
#define NGRAPH 64
#define NCLS 10

// ---------------- CSR build ----------------
// Edge list = concat(ei0, ei1) as src, concat(ei1, ei0) as dst; self-loops handled
// explicitly inside the aggregation kernels (not stored in CSR).

__global__ void hist_kernel(const int* __restrict__ ei, int E, int* __restrict__ counts) {
    int i = blockIdx.x * blockDim.x + threadIdx.x;
    if (i >= 2 * E) return;
    int dst = (i < E) ? ei[E + i] : ei[i - E];
    atomicAdd(&counts[dst], 1);
}

// Single-block exclusive scan over N counts; counts_cursor is converted in-place
// to the running cursor (== exclusive offsets), ofs[] gets offsets, ofs[N]=total.
__global__ __launch_bounds__(1024) void scan_kernel(int* __restrict__ counts_cursor,
                                                    int* __restrict__ ofs, int N) {
    __shared__ int part[1024];
    int t = threadIdx.x;
    int chunk = (N + 1023) / 1024;
    int b = t * chunk;
    int e = b + chunk; if (e > N) e = N;
    int s = 0;
    for (int i = b; i < e; ++i) s += counts_cursor[i];
    part[t] = s;
    __syncthreads();
    for (int o = 1; o < 1024; o <<= 1) {
        int v = (t >= o) ? part[t - o] : 0;
        __syncthreads();
        part[t] += v;
        __syncthreads();
    }
    int run = part[t] - s;   // exclusive prefix of this thread's chunk
    for (int i = b; i < e; ++i) {
        int c = counts_cursor[i];
        ofs[i] = run;
        counts_cursor[i] = run;  // becomes the scatter cursor
        run += c;
    }
    if (t == 1023) ofs[N] = part[1023];
}

__global__ void scatter_kernel(const int* __restrict__ ei, int E,
                               int* __restrict__ cursor, int* __restrict__ esrc) {
    int i = blockIdx.x * blockDim.x + threadIdx.x;
    if (i >= 2 * E) return;
    int src = ei[i];                                  // works for both halves
    int dst = (i < E) ? ei[E + i] : ei[i - E];
    int pos = atomicAdd(&cursor[dst], 1);
    esrc[pos] = src;
}

// ---------------- fp32 tiled GEMM: C[M,N] = A[M,K] @ B[K,N] ----------------
#define BM 64
#define BN 64
#define BK 16
#define PADL 4

__global__ __launch_bounds__(256) void sgemm_kernel(const float* __restrict__ A,
                                                    const float* __restrict__ B,
                                                    float* __restrict__ C,
                                                    int M, int N_, int K) {
    __shared__ float As[BK][BM + PADL];   // +4 pad: keeps 16B alignment, 2-way banks only
    __shared__ float Bs[BK][BN + PADL];
    const int tx = threadIdx.x & 15;
    const int ty = threadIdx.x >> 4;
    const int row0 = blockIdx.y * BM;
    const int col0 = blockIdx.x * BN;
    float acc[4][4] = {};
    for (int k0 = 0; k0 < K; k0 += BK) {
        #pragma unroll
        for (int i = threadIdx.x; i < BM * BK; i += 256) {
            int r = i >> 4, c = i & 15;
            int gr = row0 + r; if (gr >= M) gr = M - 1;   // clamp (writes are guarded)
            As[c][r] = A[(size_t)gr * K + k0 + c];
        }
        #pragma unroll
        for (int i = threadIdx.x; i < BK * BN; i += 256) {
            int r = i >> 6, c = i & 63;
            Bs[r][c] = B[(size_t)(k0 + r) * N_ + col0 + c];
        }
        __syncthreads();
        #pragma unroll
        for (int k = 0; k < BK; ++k) {
            float a[4], b[4];
            #pragma unroll
            for (int i = 0; i < 4; ++i) a[i] = As[k][ty * 4 + i];
            #pragma unroll
            for (int j = 0; j < 4; ++j) b[j] = Bs[k][tx * 4 + j];
            #pragma unroll
            for (int i = 0; i < 4; ++i)
                #pragma unroll
                for (int j = 0; j < 4; ++j) acc[i][j] += a[i] * b[j];
        }
        __syncthreads();
    }
    #pragma unroll
    for (int i = 0; i < 4; ++i) {
        int r = row0 + ty * 4 + i;
        if (r < M) {
            float4 v = make_float4(acc[i][0], acc[i][1], acc[i][2], acc[i][3]);
            *(float4*)&C[(size_t)r * N_ + col0 + tx * 4] = v;
        }
    }
}

// ---------------- attention scalars ----------------
// a_src[n,h] = dot(h1[n,h,:], att_src[h,:]); same for a_dst. One wave per node.
__global__ __launch_bounds__(256) void att1_kernel(const float* __restrict__ h1,
                                                   const float* __restrict__ att_src,
                                                   const float* __restrict__ att_dst,
                                                   float* __restrict__ as1,
                                                   float* __restrict__ ad1, int N) {
    int wave = threadIdx.x >> 6, lane = threadIdx.x & 63;
    int node = blockIdx.x * 4 + wave;
    if (node >= N) return;
    #pragma unroll
    for (int h = 0; h < HEADS; ++h) {
        float v0 = h1[(size_t)node * 512 + h * 128 + lane];
        float v1 = h1[(size_t)node * 512 + h * 128 + 64 + lane];
        float s = v0 * att_src[h * 128 + lane] + v1 * att_src[h * 128 + 64 + lane];
        float d = v0 * att_dst[h * 128 + lane] + v1 * att_dst[h * 128 + 64 + lane];
        #pragma unroll
        for (int o = 32; o > 0; o >>= 1) { s += __shfl_xor(s, o); d += __shfl_xor(d, o); }
        if (lane == 0) { as1[node * 4 + h] = s; ad1[node * 4 + h] = d; }
    }
}

__global__ __launch_bounds__(256) void att2_kernel(const float* __restrict__ h2,
                                                   const float* __restrict__ att_src,
                                                   const float* __restrict__ att_dst,
                                                   float* __restrict__ as2,
                                                   float* __restrict__ ad2, int N) {
    int wave = threadIdx.x >> 6, lane = threadIdx.x & 63;
    int node = blockIdx.x * 4 + wave;
    if (node >= N) return;
    const float4* hv4 = (const float4*)h2;
    float4 hv = hv4[(size_t)node * 64 + lane];
    float4 sv = ((const float4*)att_src)[lane];
    float4 dv = ((const float4*)att_dst)[lane];
    float s = hv.x * sv.x + hv.y * sv.y + hv.z * sv.z + hv.w * sv.w;
    float d = hv.x * dv.x + hv.y * dv.y + hv.z * dv.z + hv.w * dv.w;
    #pragma unroll
    for (int o = 32; o > 0; o >>= 1) { s += __shfl_xor(s, o); d += __shfl_xor(d, o); }
    if (lane == 0) { as2[node] = s; ad2[node] = d; }
}

// ---------------- edge softmax + aggregate ----------------
// Layer 1: one block per node, wave h handles head h. Fuses +b1 and ReLU.
__global__ __launch_bounds__(256) void edge_agg1_kernel(const float* __restrict__ h1,
                                                        const float* __restrict__ as1,
                                                        const float* __restrict__ ad1,
                                                        const int* __restrict__ ofs,
                                                        const int* __restrict__ esrc,
                                                        const float* __restrict__ b1,
                                                        float* __restrict__ ho1) {
    int node = blockIdx.x;
    int h = threadIdx.x >> 6;
    int lane = threadIdx.x & 63;
    int beg = ofs[node], end = ofs[node + 1];
    float adn = ad1[node * 4 + h];
    float es = as1[node * 4 + h] + adn; es = es > 0.f ? es : 0.2f * es;  // self-loop score
    float m = es;
    for (int e = beg + lane; e < end; e += 64) {
        int s = esrc[e];
        float v = as1[s * 4 + h] + adn; v = v > 0.f ? v : 0.2f * v;
        m = fmaxf(m, v);
    }
    #pragma unroll
    for (int o = 32; o > 0; o >>= 1) m = fmaxf(m, __shfl_xor(m, o));
    float dsum = 0.f;
    for (int e = beg + lane; e < end; e += 64) {
        int s = esrc[e];
        float v = as1[s * 4 + h] + adn; v = v > 0.f ? v : 0.2f * v;
        dsum += __expf(v - m);
    }
    #pragma unroll
    for (int o = 32; o > 0; o >>= 1) dsum += __shfl_xor(dsum, o);
    float wself = __expf(es - m);
    dsum += wself;
    size_t hb = ((size_t)node * 4 + h) * 128;
    float acc0 = wself * h1[hb + lane];
    float acc1 = wself * h1[hb + 64 + lane];
    for (int e = beg; e < end; ++e) {
        int s = esrc[e];
        float v = as1[s * 4 + h] + adn; v = v > 0.f ? v : 0.2f * v;
        float w = __expf(v - m);
        size_t sb = ((size_t)s * 4 + h) * 128;
        acc0 += w * h1[sb + lane];
        acc1 += w * h1[sb + 64 + lane];
    }
    float inv = 1.f / dsum;
    size_t o = (size_t)node * 512 + h * 128;
    float r0 = acc0 * inv + b1[h * 128 + lane];
    float r1 = acc1 * inv + b1[h * 128 + 64 + lane];
    ho1[o + lane]      = r0 > 0.f ? r0 : 0.f;   // fused inter-layer ReLU
    ho1[o + 64 + lane] = r1 > 0.f ? r1 : 0.f;
}

// Layer 2: one wave per node (1 head, C=256 -> float4 per lane). Fuses +b2 (no ReLU).
__global__ __launch_bounds__(256) void edge_agg2_kernel(const float* __restrict__ h2,
                                                        const float* __restrict__ as2,
                                                        const float* __restrict__ ad2,
                                                        const int* __restrict__ ofs,
                                                        const int* __restrict__ esrc,
                                                        const float* __restrict__ b2,
                                                        float* __restrict__ ho2, int N) {
    int wave = threadIdx.x >> 6, lane = threadIdx.x & 63;
    int node = blockIdx.x * 4 + wave;
    if (node >= N) return;
    int beg = ofs[node], end = ofs[node + 1];
    float adn = ad2[node];
    float es = as2[node] + adn; es = es > 0.f ? es : 0.2f * es;
    float m = es;
    for (int e = beg + lane; e < end; e += 64) {
        int s = esrc[e];
        float v = as2[s] + adn; v = v > 0.f ? v : 0.2f * v;
        m = fmaxf(m, v);
    }
    #pragma unroll
    for (int o = 32; o > 0; o >>= 1) m = fmaxf(m, __shfl_xor(m, o));
    float dsum = 0.f;
    for (int e = beg + lane; e < end; e += 64) {
        int s = esrc[e];
        float v = as2[s] + adn; v = v > 0.f ? v : 0.2f * v;
        dsum += __expf(v - m);
    }
    #pragma unroll
    for (int o = 32; o > 0; o >>= 1) dsum += __shfl_xor(dsum, o);
    float wself = __expf(es - m);
    dsum += wself;
    const float4* h2v = (const float4*)h2;
    float4 hv = h2v[(size_t)node * 64 + lane];
    float ax = wself * hv.x, ay = wself * hv.y, az = wself * hv.z, aw = wself * hv.w;
    for (int e = beg; e < end; ++e) {
        int s = esrc[e];
        float v = as2[s] + adn; v = v > 0.f ? v : 0.2f * v;
        float w = __expf(v - m);
        float4 sv = h2v[(size_t)s * 64 + lane];
        ax += w * sv.x; ay += w * sv.y; az += w * sv.z; aw += w * sv.w;
    }
    float inv = 1.f / dsum;
    size_t o = (size_t)node * 256 + lane * 4;
    ho2[o + 0] = ax * inv + b2[lane * 4 + 0];
    ho2[o + 1] = ay * inv + b2[lane * 4 + 1];
    ho2[o + 2] = az * inv + b2[lane * 4 + 2];
    ho2[o + 3] = aw * inv + b2[lane * 4 + 3];
}

// ---------------- global max pool (batch is sorted) ----------------
__global__ __launch_bounds__(256) void pool_kernel(const float* __restrict__ ho2,
                                                   const int* __restrict__ batch,
                                                   int N, float* __restrict__ gout) {
    int g = blockIdx.x, t = threadIdx.x;
    int lo = 0, hi = N;
    while (lo < hi) { int mid = (lo + hi) >> 1; if (batch[mid] < g) lo = mid + 1; else hi = mid; }
    int start = lo;
    lo = 0; hi = N;
    while (lo < hi) { int mid = (lo + hi) >> 1; if (batch[mid] < g + 1) lo = mid + 1; else hi = mid; }
    int end = lo;
    float m = -INFINITY;
    for (int n = start; n < end; ++n) m = fmaxf(m, ho2[(size_t)n * 256 + t]);
    gout[g * 256 + t] = m;
}

// ---------------- FC head + log_softmax ----------------
__global__ __launch_bounds__(64) void head_kernel(const float* __restrict__ gp,
                                                  const float* __restrict__ fc1w,
                                                  const float* __restrict__ fc1b,
                                                  const float* __restrict__ fc2w,
                                                  const float* __restrict__ fc2b,
                                                  float* __restrict__ out) {
    __shared__ float gr[256];
    __shared__ float hid[64];
    __shared__ float o10[NCLS];
    int g = blockIdx.x, t = threadIdx.x;
    for (int i = t; i < 256; i += 64) gr[i] = gp[g * 256 + i];
    __syncthreads();
    float s = fc1b[t];
    for (int k = 0; k < 256; ++k) s += gr[k] * fc1w[k * 64 + t];
    hid[t] = s > 0.f ? s : 0.f;
    __syncthreads();
    if (t < NCLS) {
        float s2 = fc2b[t];
        for (int k = 0; k < 64; ++k) s2 += hid[k] * fc2w[k * NCLS + t];
        o10[t] = s2;
    }
    __syncthreads();
    if (t == 0) {
        float mx = -INFINITY;
        for (int c = 0; c < NCLS; ++c) mx = fmaxf(mx, o10[c]);
        float se = 0.f;
        for (int c = 0; c < NCLS; ++c) se += __expf(o10[c] - mx);
        float lse = mx + logf(se);
        for (int c = 0; c < NCLS; ++c) out[g * NCLS + c] = o10[c] - lse;
    }
}

extern "C" void kernel_launch(void* const* d_in, const int* in_sizes, int n_in,
                              void* d_out, int out_size, void* d_ws, size_t ws_size,
                              hipStream_t stream) {
    (void)n_in; (void)out_size; (void)ws_size;
    const float* x        = (const float*)d_in[0];
    const int*   ei       = (const int*)d_in[1];
    const int*   batch    = (const int*)d_in[2];
    const float* W1       = (const float*)d_in[3];
    const float* att_src1 = (const float*)d_in[4];
    const float* att_dst1 = (const float*)d_in[5];
    const float* b1       = (const float*)d_in[6];
    const float* W2       = (const float*)d_in[7];
    const float* att_src2 = (const float*)d_in[8];
    const float* att_dst2 = (const float*)d_in[9];
    const float* b2       = (const float*)d_in[10];
    const float* fc1w     = (const float*)d_in[11];
    const float* fc1b     = (const float*)d_in[12];
    const float* fc2w     = (const float*)d_in[13];
    const float* fc2b     = (const float*)d_in[14];

    const int N = in_sizes[2];        // batch has N entries
    const int E = in_sizes[1] / 2;
    const int tot = 2 * E;

    char* base = (char*)d_ws;
    size_t off = 0;
    auto alloc = [&](size_t bytes) -> void* {
        void* p = base + off;
        off = (off + bytes + 255) & ~(size_t)255;
        return p;
    };
    int*   ofs    = (int*)alloc((size_t)(N + 1) * 4);
    int*   cursor = (int*)alloc((size_t)N * 4);            // counts -> cursor (in place)
    int*   esrc   = (int*)alloc((size_t)tot * 4);
    float* as1    = (float*)alloc((size_t)N * HEADS * 4);
    float* ad1    = (float*)alloc((size_t)N * HEADS * 4);
    float* as2    = (float*)alloc((size_t)N * 4);
    float* ad2    = (float*)alloc((size_t)N * 4);
    float* bufA   = (float*)alloc((size_t)N * 512 * 4);    // h1, then h2
    float* bufB   = (float*)alloc((size_t)N * 512 * 4);    // ho1, then ho2
    float* gpool  = (float*)alloc((size_t)NGRAPH * C2DIM * 4);

    float* h1  = bufA;
    float* ho1 = bufB;
    float* h2  = bufA;   // bufA dead after edge_agg1
    float* ho2 = bufB;   // bufB (ho1) dead after sgemm #2

    hipMemsetAsync(cursor, 0, (size_t)N * 4, stream);
    hist_kernel<<<(tot + 255) / 256, 256, 0, stream>>>(ei, E, cursor);
    scan_kernel<<<1, 1024, 0, stream>>>(cursor, ofs, N);
    scatter_kernel<<<(tot + 255) / 256, 256, 0, stream>>>(ei, E, cursor, esrc);

    // Layer 1
    dim3 g1(512 / BN, (N + BM - 1) / BM);
    sgemm_kernel<<<g1, 256, 0, stream>>>(x, W1, h1, N, 512, FDIM);
    att1_kernel<<<(N + 3) / 4, 256, 0, stream>>>(h1, att_src1, att_dst1, as1, ad1, N);
    edge_agg1_kernel<<<N, 256, 0, stream>>>(h1, as1, ad1, ofs, esrc, b1, ho1);

    // Layer 2
    dim3 g2(256 / BN, (N + BM - 1) / BM);
    sgemm_kernel<<<g2, 256, 0, stream>>>(ho1, W2, h2, N, 256, HEADS * C1DIM);
    att2_kernel<<<(N + 3) / 4, 256, 0, stream>>>(h2, att_src2, att_dst2, as2, ad2, N);
    edge_agg2_kernel<<<(N + 3) / 4, 256, 0, stream>>>(h2, as2, ad2, ofs, esrc, b2, ho2, N);

    // Pool + head
    pool_kernel<<<NGRAPH, 256, 0, stream>>>(ho2, batch, N, gpool);
    head_kernel<<<NGRAPH, 64, 0, stream>>>(gpool, fc1w, fc1b, fc2w, fc2b, (float*)d_out);
}

// Round 2
// 430.772 us; speedup vs baseline: 1.2262x; 1.2262x over previous
//
#include <hip/hip_runtime.h>
#include <math.h>

// Problem constants (reference: N=20000, E=160000, F=128, H=4, C1=128, C2=256, G=64, NCLS=10)
#define FDIM 128
#define HEADS 4
#define C1DIM 128
#define C2DIM 256
#define NGRAPH 64
#define NCLS 10

typedef __attribute__((ext_vector_type(8))) short short8;   // 8 bf16 (4 VGPRs)
typedef __attribute__((ext_vector_type(4))) float float4v;  // 4 fp32 acc

__device__ __forceinline__ unsigned short f2bf(float f) {
    unsigned u = __builtin_bit_cast(unsigned, f);
    unsigned r = (u + 0x7FFFu + ((u >> 16) & 1u)) >> 16;   // RNE
    return (unsigned short)r;
}

// ---------------- CSR build ----------------
__global__ void hist_kernel(const int* __restrict__ ei, int E, int* __restrict__ counts) {
    int i = blockIdx.x * blockDim.x + threadIdx.x;
    if (i >= 2 * E) return;
    int dst = (i < E) ? ei[E + i] : ei[i - E];
    atomicAdd(&counts[dst], 1);
}

__global__ __launch_bounds__(1024) void scan_kernel(int* __restrict__ counts_cursor,
                                                    int* __restrict__ ofs, int N) {
    __shared__ int part[1024];
    int t = threadIdx.x;
    int chunk = (N + 1023) / 1024;
    int b = t * chunk;
    int e = b + chunk; if (e > N) e = N;
    int s = 0;
    for (int i = b; i < e; ++i) s += counts_cursor[i];
    part[t] = s;
    __syncthreads();
    for (int o = 1; o < 1024; o <<= 1) {
        int v = (t >= o) ? part[t - o] : 0;
        __syncthreads();
        part[t] += v;
        __syncthreads();
    }
    int run = part[t] - s;
    for (int i = b; i < e; ++i) {
        int c = counts_cursor[i];
        ofs[i] = run;
        counts_cursor[i] = run;
        run += c;
    }
    if (t == 1023) ofs[N] = part[1023];
}

__global__ void scatter_kernel(const int* __restrict__ ei, int E,
                               int* __restrict__ cursor, int* __restrict__ esrc) {
    int i = blockIdx.x * blockDim.x + threadIdx.x;
    if (i >= 2 * E) return;
    int src = ei[i];
    int dst = (i < E) ? ei[E + i] : ei[i - E];
    int pos = atomicAdd(&cursor[dst], 1);
    esrc[pos] = src;
}

// ---------------- fp32 -> bf16 conversions ----------------
__global__ void cvt_kernel(const float* __restrict__ src, unsigned short* __restrict__ dst, int n4) {
    int i = blockIdx.x * blockDim.x + threadIdx.x;
    if (i >= n4) return;
    float4 v = ((const float4*)src)[i];
    ushort4 o;
    o.x = f2bf(v.x); o.y = f2bf(v.y); o.z = f2bf(v.z); o.w = f2bf(v.w);
    ((ushort4*)dst)[i] = o;
}

// Transpose-convert weights: W[K,N] fp32 -> Wt[N,K] bf16. Grid (N/32, K/32), block (32,8).
__global__ void tconv_kernel(const float* __restrict__ W, unsigned short* __restrict__ Wt,
                             int K, int N_) {
    __shared__ float tile[32][33];
    int bx = blockIdx.x * 32;   // n
    int by = blockIdx.y * 32;   // k
    int tx = threadIdx.x, ty = threadIdx.y;
    #pragma unroll
    for (int r = 0; r < 32; r += 8)
        tile[ty + r][tx] = W[(size_t)(by + ty + r) * N_ + bx + tx];
    __syncthreads();
    #pragma unroll
    for (int r = 0; r < 32; r += 8)
        Wt[(size_t)(bx + ty + r) * K + by + tx] = f2bf(tile[tx][ty + r]);
}

// ---------------- bf16 MFMA GEMM: C[M,N] = A[M,K] @ Bt[N,K]^T ----------------
// 128x128 tile, BK=32, 4 waves each computing 64x64 via 4x4 16x16x32 MFMAs.
// Staging via global_load_lds width=16 (wave-uniform base + lane*16 layout).
__global__ __launch_bounds__(256) void bgemm_kernel(
        const unsigned short* __restrict__ A,   // [M,K] bf16
        const unsigned short* __restrict__ Bt,  // [N,K] bf16
        float* __restrict__ C,                  // [M,N] fp32
        int M, int N_, int K) {
    __shared__ unsigned short As[128 * 32];
    __shared__ unsigned short Bs[128 * 32];
    const int t = threadIdx.x;
    const int lane = t & 63;
    const int wave = t >> 6;
    const int row0 = blockIdx.y * 128, col0 = blockIdx.x * 128;
    const int wr = (wave >> 1) * 64, wc = (wave & 1) * 64;
    float4v acc[4][4] = {};
    for (int k0 = 0; k0 < K; k0 += 32) {
        #pragma unroll
        for (int c = 0; c < 2; ++c) {
            int i = c * 256 + t;                 // 16B-chunk id, 4 chunks per 32-col row
            int gr = row0 + (i >> 2); if (gr >= M) gr = M - 1;
            const unsigned short* gp = A + (size_t)gr * K + k0 + ((i & 3) << 3);
            __builtin_amdgcn_global_load_lds(
                (const __attribute__((address_space(1))) unsigned int*)gp,
                (__attribute__((address_space(3))) unsigned int*)&As[i * 8], 16, 0, 0);
        }
        #pragma unroll
        for (int c = 0; c < 2; ++c) {
            int i = c * 256 + t;
            int gn = col0 + (i >> 2);            // N_ is a multiple of 128
            const unsigned short* gp = Bt + (size_t)gn * K + k0 + ((i & 3) << 3);
            __builtin_amdgcn_global_load_lds(
                (const __attribute__((address_space(1))) unsigned int*)gp,
                (__attribute__((address_space(3))) unsigned int*)&Bs[i * 8], 16, 0, 0);
        }
        __syncthreads();
        short8 af[4], bfr[4];
        #pragma unroll
        for (int i = 0; i < 4; ++i)
            af[i] = *(const short8*)&As[(wr + i * 16 + (lane & 15)) * 32 + (lane >> 4) * 8];
        #pragma unroll
        for (int j = 0; j < 4; ++j)
            bfr[j] = *(const short8*)&Bs[(wc + j * 16 + (lane & 15)) * 32 + (lane >> 4) * 8];
        #pragma unroll
        for (int i = 0; i < 4; ++i)
            #pragma unroll
            for (int j = 0; j < 4; ++j)
                acc[i][j] = __builtin_amdgcn_mfma_f32_16x16x32_bf16(af[i], bfr[j], acc[i][j], 0, 0, 0);
        __syncthreads();
    }
    // Epilogue: C/D layout col=lane&15, row=(lane>>4)*4+p
    #pragma unroll
    for (int i = 0; i < 4; ++i) {
        int rbase = row0 + wr + i * 16 + (lane >> 4) * 4;
        #pragma unroll
        for (int j = 0; j < 4; ++j) {
            int cc = col0 + wc + j * 16 + (lane & 15);
            #pragma unroll
            for (int p = 0; p < 4; ++p) {
                int r = rbase + p;
                if (r < M) C[(size_t)r * N_ + cc] = acc[i][j][p];
            }
        }
    }
}

// ---------------- attention scalars ----------------
__global__ __launch_bounds__(256) void att1_kernel(const float* __restrict__ h1,
                                                   const float* __restrict__ att_src,
                                                   const float* __restrict__ att_dst,
                                                   float* __restrict__ as1,
                                                   float* __restrict__ ad1, int N) {
    int wave = threadIdx.x >> 6, lane = threadIdx.x & 63;
    int node = blockIdx.x * 4 + wave;
    if (node >= N) return;
    #pragma unroll
    for (int h = 0; h < HEADS; ++h) {
        float v0 = h1[(size_t)node * 512 + h * 128 + lane];
        float v1 = h1[(size_t)node * 512 + h * 128 + 64 + lane];
        float s = v0 * att_src[h * 128 + lane] + v1 * att_src[h * 128 + 64 + lane];
        float d = v0 * att_dst[h * 128 + lane] + v1 * att_dst[h * 128 + 64 + lane];
        #pragma unroll
        for (int o = 32; o > 0; o >>= 1) { s += __shfl_xor(s, o); d += __shfl_xor(d, o); }
        if (lane == 0) { as1[node * 4 + h] = s; ad1[node * 4 + h] = d; }
    }
}

__global__ __launch_bounds__(256) void att2_kernel(const float* __restrict__ h2,
                                                   const float* __restrict__ att_src,
                                                   const float* __restrict__ att_dst,
                                                   float* __restrict__ as2,
                                                   float* __restrict__ ad2, int N) {
    int wave = threadIdx.x >> 6, lane = threadIdx.x & 63;
    int node = blockIdx.x * 4 + wave;
    if (node >= N) return;
    const float4* hv4 = (const float4*)h2;
    float4 hv = hv4[(size_t)node * 64 + lane];
    float4 sv = ((const float4*)att_src)[lane];
    float4 dv = ((const float4*)att_dst)[lane];
    float s = hv.x * sv.x + hv.y * sv.y + hv.z * sv.z + hv.w * sv.w;
    float d = hv.x * dv.x + hv.y * dv.y + hv.z * dv.z + hv.w * dv.w;
    #pragma unroll
    for (int o = 32; o > 0; o >>= 1) { s += __shfl_xor(s, o); d += __shfl_xor(d, o); }
    if (lane == 0) { as2[node] = s; ad2[node] = d; }
}

// ---------------- edge softmax + aggregate ----------------
// Layer 1: one block per node, wave h handles head h. Fuses +b1, ReLU, bf16 cast.
__global__ __launch_bounds__(256) void edge_agg1_kernel(const float* __restrict__ h1,
                                                        const float* __restrict__ as1,
                                                        const float* __restrict__ ad1,
                                                        const int* __restrict__ ofs,
                                                        const int* __restrict__ esrc,
                                                        const float* __restrict__ b1,
                                                        unsigned short* __restrict__ ho1b) {
    int node = blockIdx.x;
    int h = threadIdx.x >> 6;
    int lane = threadIdx.x & 63;
    int beg = ofs[node], end = ofs[node + 1];
    float adn = ad1[node * 4 + h];
    float es = as1[node * 4 + h] + adn; es = es > 0.f ? es : 0.2f * es;
    float m = es;
    for (int e = beg + lane; e < end; e += 64) {
        int s = esrc[e];
        float v = as1[s * 4 + h] + adn; v = v > 0.f ? v : 0.2f * v;
        m = fmaxf(m, v);
    }
    #pragma unroll
    for (int o = 32; o > 0; o >>= 1) m = fmaxf(m, __shfl_xor(m, o));
    float dsum = 0.f;
    for (int e = beg + lane; e < end; e += 64) {
        int s = esrc[e];
        float v = as1[s * 4 + h] + adn; v = v > 0.f ? v : 0.2f * v;
        dsum += __expf(v - m);
    }
    #pragma unroll
    for (int o = 32; o > 0; o >>= 1) dsum += __shfl_xor(dsum, o);
    float wself = __expf(es - m);
    dsum += wself;
    size_t hb = ((size_t)node * 4 + h) * 128;
    float acc0 = wself * h1[hb + lane];
    float acc1 = wself * h1[hb + 64 + lane];
    for (int e = beg; e < end; ++e) {
        int s = esrc[e];
        float v = as1[s * 4 + h] + adn; v = v > 0.f ? v : 0.2f * v;
        float w = __expf(v - m);
        size_t sb = ((size_t)s * 4 + h) * 128;
        acc0 += w * h1[sb + lane];
        acc1 += w * h1[sb + 64 + lane];
    }
    float inv = 1.f / dsum;
    size_t o = (size_t)node * 512 + h * 128;
    float r0 = acc0 * inv + b1[h * 128 + lane];
    float r1 = acc1 * inv + b1[h * 128 + 64 + lane];
    ho1b[o + lane]      = f2bf(r0 > 0.f ? r0 : 0.f);   // fused ReLU + bf16
    ho1b[o + 64 + lane] = f2bf(r1 > 0.f ? r1 : 0.f);
}

// Layer 2: one wave per node (1 head, C=256 -> float4 per lane). Fuses +b2.
__global__ __launch_bounds__(256) void edge_agg2_kernel(const float* __restrict__ h2,
                                                        const float* __restrict__ as2,
                                                        const float* __restrict__ ad2,
                                                        const int* __restrict__ ofs,
                                                        const int* __restrict__ esrc,
                                                        const float* __restrict__ b2,
                                                        float* __restrict__ ho2, int N) {
    int wave = threadIdx.x >> 6, lane = threadIdx.x & 63;
    int node = blockIdx.x * 4 + wave;
    if (node >= N) return;
    int beg = ofs[node], end = ofs[node + 1];
    float adn = ad2[node];
    float es = as2[node] + adn; es = es > 0.f ? es : 0.2f * es;
    float m = es;
    for (int e = beg + lane; e < end; e += 64) {
        int s = esrc[e];
        float v = as2[s] + adn; v = v > 0.f ? v : 0.2f * v;
        m = fmaxf(m, v);
    }
    #pragma unroll
    for (int o = 32; o > 0; o >>= 1) m = fmaxf(m, __shfl_xor(m, o));
    float dsum = 0.f;
    for (int e = beg + lane; e < end; e += 64) {
        int s = esrc[e];
        float v = as2[s] + adn; v = v > 0.f ? v : 0.2f * v;
        dsum += __expf(v - m);
    }
    #pragma unroll
    for (int o = 32; o > 0; o >>= 1) dsum += __shfl_xor(dsum, o);
    float wself = __expf(es - m);
    dsum += wself;
    const float4* h2v = (const float4*)h2;
    float4 hv = h2v[(size_t)node * 64 + lane];
    float ax = wself * hv.x, ay = wself * hv.y, az = wself * hv.z, aw = wself * hv.w;
    for (int e = beg; e < end; ++e) {
        int s = esrc[e];
        float v = as2[s] + adn; v = v > 0.f ? v : 0.2f * v;
        float w = __expf(v - m);
        float4 sv = h2v[(size_t)s * 64 + lane];
        ax += w * sv.x; ay += w * sv.y; az += w * sv.z; aw += w * sv.w;
    }
    float inv = 1.f / dsum;
    size_t o = (size_t)node * 256 + lane * 4;
    ho2[o + 0] = ax * inv + b2[lane * 4 + 0];
    ho2[o + 1] = ay * inv + b2[lane * 4 + 1];
    ho2[o + 2] = az * inv + b2[lane * 4 + 2];
    ho2[o + 3] = aw * inv + b2[lane * 4 + 3];
}

// ---------------- global max pool (batch is sorted) ----------------
__global__ __launch_bounds__(256) void pool_kernel(const float* __restrict__ ho2,
                                                   const int* __restrict__ batch,
                                                   int N, float* __restrict__ gout) {
    int g = blockIdx.x, t = threadIdx.x;
    int lo = 0, hi = N;
    while (lo < hi) { int mid = (lo + hi) >> 1; if (batch[mid] < g) lo = mid + 1; else hi = mid; }
    int start = lo;
    lo = 0; hi = N;
    while (lo < hi) { int mid = (lo + hi) >> 1; if (batch[mid] < g + 1) lo = mid + 1; else hi = mid; }
    int end = lo;
    float m = -INFINITY;
    for (int n = start; n < end; ++n) m = fmaxf(m, ho2[(size_t)n * 256 + t]);
    gout[g * 256 + t] = m;
}

// ---------------- FC head + log_softmax ----------------
__global__ __launch_bounds__(64) void head_kernel(const float* __restrict__ gp,
                                                  const float* __restrict__ fc1w,
                                                  const float* __restrict__ fc1b,
                                                  const float* __restrict__ fc2w,
                                                  const float* __restrict__ fc2b,
                                                  float* __restrict__ out) {
    __shared__ float gr[256];
    __shared__ float hid[64];
    __shared__ float o10[NCLS];
    int g = blockIdx.x, t = threadIdx.x;
    for (int i = t; i < 256; i += 64) gr[i] = gp[g * 256 + i];
    __syncthreads();
    float s = fc1b[t];
    for (int k = 0; k < 256; ++k) s += gr[k] * fc1w[k * 64 + t];
    hid[t] = s > 0.f ? s : 0.f;
    __syncthreads();
    if (t < NCLS) {
        float s2 = fc2b[t];
        for (int k = 0; k < 64; ++k) s2 += hid[k] * fc2w[k * NCLS + t];
        o10[t] = s2;
    }
    __syncthreads();
    if (t == 0) {
        float mx = -INFINITY;
        for (int c = 0; c < NCLS; ++c) mx = fmaxf(mx, o10[c]);
        float se = 0.f;
        for (int c = 0; c < NCLS; ++c) se += __expf(o10[c] - mx);
        float lse = mx + logf(se);
        for (int c = 0; c < NCLS; ++c) out[g * NCLS + c] = o10[c] - lse;
    }
}

extern "C" void kernel_launch(void* const* d_in, const int* in_sizes, int n_in,
                              void* d_out, int out_size, void* d_ws, size_t ws_size,
                              hipStream_t stream) {
    (void)n_in; (void)out_size; (void)ws_size;
    const float* x        = (const float*)d_in[0];
    const int*   ei       = (const int*)d_in[1];
    const int*   batch    = (const int*)d_in[2];
    const float* W1       = (const float*)d_in[3];
    const float* att_src1 = (const float*)d_in[4];
    const float* att_dst1 = (const float*)d_in[5];
    const float* b1       = (const float*)d_in[6];
    const float* W2       = (const float*)d_in[7];
    const float* att_src2 = (const float*)d_in[8];
    const float* att_dst2 = (const float*)d_in[9];
    const float* b2       = (const float*)d_in[10];
    const float* fc1w     = (const float*)d_in[11];
    const float* fc1b     = (const float*)d_in[12];
    const float* fc2w     = (const float*)d_in[13];
    const float* fc2b     = (const float*)d_in[14];

    const int N = in_sizes[2];
    const int E = in_sizes[1] / 2;
    const int tot = 2 * E;

    char* base = (char*)d_ws;
    size_t off = 0;
    auto alloc = [&](size_t bytes) -> void* {
        void* p = base + off;
        off = (off + bytes + 255) & ~(size_t)255;
        return p;
    };
    int*   ofs    = (int*)alloc((size_t)(N + 1) * 4);
    int*   cursor = (int*)alloc((size_t)N * 4);
    int*   esrc   = (int*)alloc((size_t)tot * 4);
    float* as1    = (float*)alloc((size_t)N * HEADS * 4);
    float* ad1    = (float*)alloc((size_t)N * HEADS * 4);
    float* as2    = (float*)alloc((size_t)N * 4);
    float* ad2    = (float*)alloc((size_t)N * 4);
    unsigned short* xb   = (unsigned short*)alloc((size_t)N * FDIM * 2);
    unsigned short* W1t  = (unsigned short*)alloc((size_t)512 * 128 * 2);
    unsigned short* W2t  = (unsigned short*)alloc((size_t)256 * 512 * 2);
    unsigned short* ho1b = (unsigned short*)alloc((size_t)N * 512 * 2);
    float* bufA   = (float*)alloc((size_t)N * 512 * 4);    // h1; later h2 (first half) + ho2 (second half)
    float* gpool  = (float*)alloc((size_t)NGRAPH * C2DIM * 4);

    float* h1  = bufA;
    float* h2  = bufA;                    // h1 dead after edge_agg1
    float* ho2 = bufA + (size_t)N * 256;  // coexists with h2 in bufA (each N*256 floats)

    // CSR build
    hipMemsetAsync(cursor, 0, (size_t)N * 4, stream);
    hist_kernel<<<(tot + 255) / 256, 256, 0, stream>>>(ei, E, cursor);
    scan_kernel<<<1, 1024, 0, stream>>>(cursor, ofs, N);
    scatter_kernel<<<(tot + 255) / 256, 256, 0, stream>>>(ei, E, cursor, esrc);

    // bf16 conversions
    cvt_kernel<<<(N * FDIM / 4 + 255) / 256, 256, 0, stream>>>(x, xb, N * FDIM / 4);
    tconv_kernel<<<dim3(512 / 32, 128 / 32), dim3(32, 8), 0, stream>>>(W1, W1t, 128, 512);
    tconv_kernel<<<dim3(256 / 32, 512 / 32), dim3(32, 8), 0, stream>>>(W2, W2t, 512, 256);

    // Layer 1: h1 = x @ W1  (M=N, N=512, K=128)
    bgemm_kernel<<<dim3(512 / 128, (N + 127) / 128), 256, 0, stream>>>(xb, W1t, h1, N, 512, 128);
    att1_kernel<<<(N + 3) / 4, 256, 0, stream>>>(h1, att_src1, att_dst1, as1, ad1, N);
    edge_agg1_kernel<<<N, 256, 0, stream>>>(h1, as1, ad1, ofs, esrc, b1, ho1b);

    // Layer 2: h2 = ho1 @ W2  (M=N, N=256, K=512)
    bgemm_kernel<<<dim3(256 / 128, (N + 127) / 128), 256, 0, stream>>>(ho1b, W2t, h2, N, 256, 512);
    att2_kernel<<<(N + 3) / 4, 256, 0, stream>>>(h2, att_src2, att_dst2, as2, ad2, N);
    edge_agg2_kernel<<<(N + 3) / 4, 256, 0, stream>>>(h2, as2, ad2, ofs, esrc, b2, ho2, N);

    // Pool + head
    pool_kernel<<<NGRAPH, 256, 0, stream>>>(ho2, batch, N, gpool);
    head_kernel<<<NGRAPH, 64, 0, stream>>>(gpool, fc1w, fc1b, fc2w, fc2b, (float*)d_out);
}

// Round 3
// 344.252 us; speedup vs baseline: 1.5344x; 1.2513x over previous
//
#include <hip/hip_runtime.h>
#include <math.h>

// Problem constants (reference: N=20000, E=160000, F=128, H=4, C1=128, C2=256, G=64, NCLS=10)
#define FDIM 128
#define HEADS 4
#define C1DIM 128
#define C2DIM 256
#define NGRAPH 64
#define NCLS 10

typedef __attribute__((ext_vector_type(8))) short short8;   // 8 bf16 (4 VGPRs)
typedef __attribute__((ext_vector_type(4))) float float4v;  // 4 fp32 acc

__device__ __forceinline__ unsigned short f2bf(float f) {
    unsigned u = __builtin_bit_cast(unsigned, f);
    unsigned r = (u + 0x7FFFu + ((u >> 16) & 1u)) >> 16;   // RNE
    return (unsigned short)r;
}
__device__ __forceinline__ float bflo(int u) { return __builtin_bit_cast(float, (unsigned)u << 16); }
__device__ __forceinline__ float bfhi(int u) { return __builtin_bit_cast(float, (unsigned)u & 0xffff0000u); }
__device__ __forceinline__ float lrelu(float x) { return x > 0.f ? x : 0.2f * x; }

// ---------------- CSR build ----------------
__global__ void hist_kernel(const int* __restrict__ ei, int E, int* __restrict__ counts) {
    int i = blockIdx.x * blockDim.x + threadIdx.x;
    if (i >= 2 * E) return;
    int dst = (i < E) ? ei[E + i] : ei[i - E];
    atomicAdd(&counts[dst], 1);
}

__global__ __launch_bounds__(1024) void scan_kernel(int* __restrict__ counts_cursor,
                                                    int* __restrict__ ofs, int N) {
    __shared__ int part[1024];
    int t = threadIdx.x;
    int chunk = (N + 1023) / 1024;
    int b = t * chunk;
    int e = b + chunk; if (e > N) e = N;
    int s = 0;
    for (int i = b; i < e; ++i) s += counts_cursor[i];
    part[t] = s;
    __syncthreads();
    for (int o = 1; o < 1024; o <<= 1) {
        int v = (t >= o) ? part[t - o] : 0;
        __syncthreads();
        part[t] += v;
        __syncthreads();
    }
    int run = part[t] - s;
    for (int i = b; i < e; ++i) {
        int c = counts_cursor[i];
        ofs[i] = run;
        counts_cursor[i] = run;
        run += c;
    }
    if (t == 1023) ofs[N] = part[1023];
}

__global__ void scatter_kernel(const int* __restrict__ ei, int E,
                               int* __restrict__ cursor, int* __restrict__ esrc) {
    int i = blockIdx.x * blockDim.x + threadIdx.x;
    if (i >= 2 * E) return;
    int src = ei[i];
    int dst = (i < E) ? ei[E + i] : ei[i - E];
    int pos = atomicAdd(&cursor[dst], 1);
    esrc[pos] = src;
}

// ---------------- fp32 -> bf16 conversions ----------------
__global__ void cvt_kernel(const float* __restrict__ src, unsigned short* __restrict__ dst, int n4) {
    int i = blockIdx.x * blockDim.x + threadIdx.x;
    if (i >= n4) return;
    float4 v = ((const float4*)src)[i];
    ushort4 o;
    o.x = f2bf(v.x); o.y = f2bf(v.y); o.z = f2bf(v.z); o.w = f2bf(v.w);
    ((ushort4*)dst)[i] = o;
}

// Transpose-convert weights: W[K,N] fp32 -> Wt[N,K] bf16. Grid (N/32, K/32), block (32,8).
__global__ void tconv_kernel(const float* __restrict__ W, unsigned short* __restrict__ Wt,
                             int K, int N_) {
    __shared__ float tile[32][33];
    int bx = blockIdx.x * 32;
    int by = blockIdx.y * 32;
    int tx = threadIdx.x, ty = threadIdx.y;
    #pragma unroll
    for (int r = 0; r < 32; r += 8)
        tile[ty + r][tx] = W[(size_t)(by + ty + r) * N_ + bx + tx];
    __syncthreads();
    #pragma unroll
    for (int r = 0; r < 32; r += 8)
        Wt[(size_t)(bx + ty + r) * K + by + tx] = f2bf(tile[tx][ty + r]);
}

// ---------------- bf16 MFMA GEMM: C[M,N] = A[M,K] @ Bt[N,K]^T, bf16 out ----------------
__global__ __launch_bounds__(256) void bgemm_kernel(
        const unsigned short* __restrict__ A,   // [M,K] bf16
        const unsigned short* __restrict__ Bt,  // [N,K] bf16
        unsigned short* __restrict__ C,         // [M,N] bf16
        int M, int N_, int K) {
    __shared__ unsigned short As[128 * 32];
    __shared__ unsigned short Bs[128 * 32];
    const int t = threadIdx.x;
    const int lane = t & 63;
    const int wave = t >> 6;
    const int row0 = blockIdx.y * 128, col0 = blockIdx.x * 128;
    const int wr = (wave >> 1) * 64, wc = (wave & 1) * 64;
    float4v acc[4][4] = {};
    for (int k0 = 0; k0 < K; k0 += 32) {
        #pragma unroll
        for (int c = 0; c < 2; ++c) {
            int i = c * 256 + t;
            int gr = row0 + (i >> 2); if (gr >= M) gr = M - 1;
            const unsigned short* gp = A + (size_t)gr * K + k0 + ((i & 3) << 3);
            __builtin_amdgcn_global_load_lds(
                (const __attribute__((address_space(1))) unsigned int*)gp,
                (__attribute__((address_space(3))) unsigned int*)&As[i * 8], 16, 0, 0);
        }
        #pragma unroll
        for (int c = 0; c < 2; ++c) {
            int i = c * 256 + t;
            int gn = col0 + (i >> 2);
            const unsigned short* gp = Bt + (size_t)gn * K + k0 + ((i & 3) << 3);
            __builtin_amdgcn_global_load_lds(
                (const __attribute__((address_space(1))) unsigned int*)gp,
                (__attribute__((address_space(3))) unsigned int*)&Bs[i * 8], 16, 0, 0);
        }
        __syncthreads();
        short8 af[4], bfr[4];
        #pragma unroll
        for (int i = 0; i < 4; ++i)
            af[i] = *(const short8*)&As[(wr + i * 16 + (lane & 15)) * 32 + (lane >> 4) * 8];
        #pragma unroll
        for (int j = 0; j < 4; ++j)
            bfr[j] = *(const short8*)&Bs[(wc + j * 16 + (lane & 15)) * 32 + (lane >> 4) * 8];
        #pragma unroll
        for (int i = 0; i < 4; ++i)
            #pragma unroll
            for (int j = 0; j < 4; ++j)
                acc[i][j] = __builtin_amdgcn_mfma_f32_16x16x32_bf16(af[i], bfr[j], acc[i][j], 0, 0, 0);
        __syncthreads();
    }
    #pragma unroll
    for (int i = 0; i < 4; ++i) {
        int rbase = row0 + wr + i * 16 + (lane >> 4) * 4;
        #pragma unroll
        for (int j = 0; j < 4; ++j) {
            int cc = col0 + wc + j * 16 + (lane & 15);
            #pragma unroll
            for (int p = 0; p < 4; ++p) {
                int r = rbase + p;
                if (r < M) C[(size_t)r * N_ + cc] = f2bf(acc[i][j][p]);
            }
        }
    }
}

// ---------------- attention scalars (bf16 inputs) ----------------
// Layer 1: one wave per node, lane covers 8 channels of the 512; head = lane>>4.
__global__ __launch_bounds__(256) void att1_kernel(const unsigned short* __restrict__ h1b,
                                                   const float* __restrict__ att_src,
                                                   const float* __restrict__ att_dst,
                                                   float* __restrict__ as1,
                                                   float* __restrict__ ad1, int N) {
    int wave = threadIdx.x >> 6, lane = threadIdx.x & 63;
    int node = blockIdx.x * 4 + wave;
    if (node >= N) return;
    int c0 = lane * 8;
    int4 r = *(const int4*)&h1b[(size_t)node * 512 + c0];
    float f0 = bflo(r.x), f1 = bfhi(r.x), f2 = bflo(r.y), f3 = bfhi(r.y);
    float f4 = bflo(r.z), f5 = bfhi(r.z), f6 = bflo(r.w), f7 = bfhi(r.w);
    float4 sA = *(const float4*)&att_src[c0], sB = *(const float4*)&att_src[c0 + 4];
    float4 dA = *(const float4*)&att_dst[c0], dB = *(const float4*)&att_dst[c0 + 4];
    float s = f0 * sA.x + f1 * sA.y + f2 * sA.z + f3 * sA.w
            + f4 * sB.x + f5 * sB.y + f6 * sB.z + f7 * sB.w;
    float d = f0 * dA.x + f1 * dA.y + f2 * dA.z + f3 * dA.w
            + f4 * dB.x + f5 * dB.y + f6 * dB.z + f7 * dB.w;
    #pragma unroll
    for (int o = 1; o <= 8; o <<= 1) { s += __shfl_xor(s, o); d += __shfl_xor(d, o); }
    if ((lane & 15) == 0) {
        int hd = lane >> 4;
        as1[node * 4 + hd] = s;
        ad1[node * 4 + hd] = d;
    }
}

__global__ __launch_bounds__(256) void att2_kernel(const unsigned short* __restrict__ h2b,
                                                   const float* __restrict__ att_src,
                                                   const float* __restrict__ att_dst,
                                                   float* __restrict__ as2,
                                                   float* __restrict__ ad2, int N) {
    int wave = threadIdx.x >> 6, lane = threadIdx.x & 63;
    int node = blockIdx.x * 4 + wave;
    if (node >= N) return;
    int c0 = lane * 4;
    int2 r = *(const int2*)&h2b[(size_t)node * 256 + c0];
    float f0 = bflo(r.x), f1 = bfhi(r.x), f2 = bflo(r.y), f3 = bfhi(r.y);
    float4 sv = *(const float4*)&att_src[c0];
    float4 dv = *(const float4*)&att_dst[c0];
    float s = f0 * sv.x + f1 * sv.y + f2 * sv.z + f3 * sv.w;
    float d = f0 * dv.x + f1 * dv.y + f2 * dv.z + f3 * dv.w;
    #pragma unroll
    for (int o = 32; o > 0; o >>= 1) { s += __shfl_xor(s, o); d += __shfl_xor(d, o); }
    if (lane == 0) { as2[node] = s; ad2[node] = d; }
}

// ---------------- edge softmax + aggregate ----------------
// Layer 1: one WAVE per node (all 4 heads). Lane = 8 channels; head = lane>>4.
// Per-edge scores computed once (as1 row = contiguous float4), staged via LDS.
__global__ __launch_bounds__(256) void edge_agg1_kernel(
        const unsigned short* __restrict__ h1b,   // [N,512] bf16
        const float4* __restrict__ as14,          // [N] (as1 rows)
        const float4* __restrict__ ad14,
        const int* __restrict__ ofs,
        const int* __restrict__ esrc,
        const float* __restrict__ b1,
        unsigned short* __restrict__ ho1b, int N) {
    __shared__ float wbuf[4][256];
    __shared__ int   sbuf[4][64];
    __shared__ int   degs[4];
    int wave = threadIdx.x >> 6, lane = threadIdx.x & 63;
    int node = blockIdx.x * 4 + wave;
    bool valid = node < N;
    int beg = 0, end = 0;
    if (valid) { beg = ofs[node]; end = ofs[node + 1]; }
    int deg = end - beg;
    if (lane == 0) degs[wave] = deg;
    __syncthreads();
    int maxdeg = max(max(degs[0], degs[1]), max(degs[2], degs[3]));

    float4 adn = make_float4(0.f, 0.f, 0.f, 0.f), asn = adn;
    if (valid) { adn = ad14[node]; asn = as14[node]; }
    float es0 = lrelu(asn.x + adn.x), es1 = lrelu(asn.y + adn.y);
    float es2 = lrelu(asn.z + adn.z), es3 = lrelu(asn.w + adn.w);
    float m0 = es0, m1 = es1, m2 = es2, m3 = es3;
    for (int e = beg + lane; e < end; e += 64) {
        int s = esrc[e];
        float4 a = as14[s];
        m0 = fmaxf(m0, lrelu(a.x + adn.x));
        m1 = fmaxf(m1, lrelu(a.y + adn.y));
        m2 = fmaxf(m2, lrelu(a.z + adn.z));
        m3 = fmaxf(m3, lrelu(a.w + adn.w));
    }
    #pragma unroll
    for (int o = 32; o > 0; o >>= 1) {
        m0 = fmaxf(m0, __shfl_xor(m0, o));
        m1 = fmaxf(m1, __shfl_xor(m1, o));
        m2 = fmaxf(m2, __shfl_xor(m2, o));
        m3 = fmaxf(m3, __shfl_xor(m3, o));
    }
    int hd = lane >> 4;
    int c0 = lane * 8;
    float w0 = __expf(es0 - m0), w1 = __expf(es1 - m1);
    float w2 = __expf(es2 - m2), w3 = __expf(es3 - m3);
    float wsh = hd == 0 ? w0 : hd == 1 ? w1 : hd == 2 ? w2 : w3;

    float acc[8] = {0.f, 0.f, 0.f, 0.f, 0.f, 0.f, 0.f, 0.f};
    if (valid) {
        int4 r = *(const int4*)&h1b[(size_t)node * 512 + c0];
        acc[0] = wsh * bflo(r.x); acc[1] = wsh * bfhi(r.x);
        acc[2] = wsh * bflo(r.y); acc[3] = wsh * bfhi(r.y);
        acc[4] = wsh * bflo(r.z); acc[5] = wsh * bfhi(r.z);
        acc[6] = wsh * bflo(r.w); acc[7] = wsh * bfhi(r.w);
    }
    float d0 = 0.f, d1 = 0.f, d2 = 0.f, d3 = 0.f;
    for (int cb = 0; cb < maxdeg; cb += 64) {
        __syncthreads();
        float4 w = make_float4(0.f, 0.f, 0.f, 0.f);
        int s = 0;
        if (cb + lane < deg) {
            s = esrc[beg + cb + lane];
            float4 a = as14[s];
            w.x = __expf(lrelu(a.x + adn.x) - m0);
            w.y = __expf(lrelu(a.y + adn.y) - m1);
            w.z = __expf(lrelu(a.z + adn.z) - m2);
            w.w = __expf(lrelu(a.w + adn.w) - m3);
            d0 += w.x; d1 += w.y; d2 += w.z; d3 += w.w;
        }
        *(float4*)&wbuf[wave][lane * 4] = w;
        sbuf[wave][lane] = s;
        __syncthreads();
        int jmax = deg - cb; if (jmax > 64) jmax = 64;
        for (int j = 0; j < jmax; ++j) {
            int ss = sbuf[wave][j];
            float wj = wbuf[wave][j * 4 + hd];
            int4 r = *(const int4*)&h1b[(size_t)ss * 512 + c0];
            acc[0] += wj * bflo(r.x); acc[1] += wj * bfhi(r.x);
            acc[2] += wj * bflo(r.y); acc[3] += wj * bfhi(r.y);
            acc[4] += wj * bflo(r.z); acc[5] += wj * bfhi(r.z);
            acc[6] += wj * bflo(r.w); acc[7] += wj * bfhi(r.w);
        }
    }
    #pragma unroll
    for (int o = 32; o > 0; o >>= 1) {
        d0 += __shfl_xor(d0, o); d1 += __shfl_xor(d1, o);
        d2 += __shfl_xor(d2, o); d3 += __shfl_xor(d3, o);
    }
    d0 += w0; d1 += w1; d2 += w2; d3 += w3;
    float dh = hd == 0 ? d0 : hd == 1 ? d1 : hd == 2 ? d2 : d3;
    float inv = 1.f / dh;
    if (valid) {
        float4 bA = *(const float4*)&b1[c0], bB = *(const float4*)&b1[c0 + 4];
        float v0 = fmaxf(acc[0] * inv + bA.x, 0.f), v1 = fmaxf(acc[1] * inv + bA.y, 0.f);
        float v2 = fmaxf(acc[2] * inv + bA.z, 0.f), v3 = fmaxf(acc[3] * inv + bA.w, 0.f);
        float v4 = fmaxf(acc[4] * inv + bB.x, 0.f), v5 = fmaxf(acc[5] * inv + bB.y, 0.f);
        float v6 = fmaxf(acc[6] * inv + bB.z, 0.f), v7 = fmaxf(acc[7] * inv + bB.w, 0.f);
        int4 o;
        o.x = (int)((unsigned)f2bf(v0) | ((unsigned)f2bf(v1) << 16));
        o.y = (int)((unsigned)f2bf(v2) | ((unsigned)f2bf(v3) << 16));
        o.z = (int)((unsigned)f2bf(v4) | ((unsigned)f2bf(v5) << 16));
        o.w = (int)((unsigned)f2bf(v6) | ((unsigned)f2bf(v7) << 16));
        *(int4*)&ho1b[(size_t)node * 512 + c0] = o;
    }
}

// Layer 2: one wave per node, 1 head, lane = 4 channels of 256 (bf16 gather).
__global__ __launch_bounds__(256) void edge_agg2_kernel(
        const unsigned short* __restrict__ h2b,   // [N,256] bf16
        const float* __restrict__ as2,
        const float* __restrict__ ad2,
        const int* __restrict__ ofs,
        const int* __restrict__ esrc,
        const float* __restrict__ b2,
        float* __restrict__ ho2, int N) {
    __shared__ float wbuf[4][64];
    __shared__ int   sbuf[4][64];
    __shared__ int   degs[4];
    int wave = threadIdx.x >> 6, lane = threadIdx.x & 63;
    int node = blockIdx.x * 4 + wave;
    bool valid = node < N;
    int beg = 0, end = 0;
    if (valid) { beg = ofs[node]; end = ofs[node + 1]; }
    int deg = end - beg;
    if (lane == 0) degs[wave] = deg;
    __syncthreads();
    int maxdeg = max(max(degs[0], degs[1]), max(degs[2], degs[3]));

    float adn = valid ? ad2[node] : 0.f;
    float asn = valid ? as2[node] : 0.f;
    float es = lrelu(asn + adn);
    float m = es;
    for (int e = beg + lane; e < end; e += 64) {
        int s = esrc[e];
        m = fmaxf(m, lrelu(as2[s] + adn));
    }
    #pragma unroll
    for (int o = 32; o > 0; o >>= 1) m = fmaxf(m, __shfl_xor(m, o));
    float wself = __expf(es - m);
    int c0 = lane * 4;
    float a0 = 0.f, a1 = 0.f, a2 = 0.f, a3 = 0.f;
    if (valid) {
        int2 r = *(const int2*)&h2b[(size_t)node * 256 + c0];
        a0 = wself * bflo(r.x); a1 = wself * bfhi(r.x);
        a2 = wself * bflo(r.y); a3 = wself * bfhi(r.y);
    }
    float dsum = 0.f;
    for (int cb = 0; cb < maxdeg; cb += 64) {
        __syncthreads();
        float w = 0.f; int s = 0;
        if (cb + lane < deg) {
            s = esrc[beg + cb + lane];
            w = __expf(lrelu(as2[s] + adn) - m);
            dsum += w;
        }
        wbuf[wave][lane] = w;
        sbuf[wave][lane] = s;
        __syncthreads();
        int jmax = deg - cb; if (jmax > 64) jmax = 64;
        for (int j = 0; j < jmax; ++j) {
            int ss = sbuf[wave][j];
            float wj = wbuf[wave][j];
            int2 r = *(const int2*)&h2b[(size_t)ss * 256 + c0];
            a0 += wj * bflo(r.x); a1 += wj * bfhi(r.x);
            a2 += wj * bflo(r.y); a3 += wj * bfhi(r.y);
        }
    }
    #pragma unroll
    for (int o = 32; o > 0; o >>= 1) dsum += __shfl_xor(dsum, o);
    dsum += wself;
    if (valid) {
        float inv = 1.f / dsum;
        float4 bv = *(const float4*)&b2[c0];
        float4 o;
        o.x = a0 * inv + bv.x; o.y = a1 * inv + bv.y;
        o.z = a2 * inv + bv.z; o.w = a3 * inv + bv.w;
        *(float4*)&ho2[(size_t)node * 256 + c0] = o;
    }
}

// ---------------- global max pool (batch is sorted) ----------------
__global__ __launch_bounds__(256) void pool_kernel(const float* __restrict__ ho2,
                                                   const int* __restrict__ batch,
                                                   int N, float* __restrict__ gout) {
    int g = blockIdx.x, t = threadIdx.x;
    int lo = 0, hi = N;
    while (lo < hi) { int mid = (lo + hi) >> 1; if (batch[mid] < g) lo = mid + 1; else hi = mid; }
    int start = lo;
    lo = 0; hi = N;
    while (lo < hi) { int mid = (lo + hi) >> 1; if (batch[mid] < g + 1) lo = mid + 1; else hi = mid; }
    int end = lo;
    float m = -INFINITY;
    for (int n = start; n < end; ++n) m = fmaxf(m, ho2[(size_t)n * 256 + t]);
    gout[g * 256 + t] = m;
}

// ---------------- FC head + log_softmax ----------------
__global__ __launch_bounds__(64) void head_kernel(const float* __restrict__ gp,
                                                  const float* __restrict__ fc1w,
                                                  const float* __restrict__ fc1b,
                                                  const float* __restrict__ fc2w,
                                                  const float* __restrict__ fc2b,
                                                  float* __restrict__ out) {
    __shared__ float gr[256];
    __shared__ float hid[64];
    __shared__ float o10[NCLS];
    int g = blockIdx.x, t = threadIdx.x;
    for (int i = t; i < 256; i += 64) gr[i] = gp[g * 256 + i];
    __syncthreads();
    float s = fc1b[t];
    for (int k = 0; k < 256; ++k) s += gr[k] * fc1w[k * 64 + t];
    hid[t] = s > 0.f ? s : 0.f;
    __syncthreads();
    if (t < NCLS) {
        float s2 = fc2b[t];
        for (int k = 0; k < 64; ++k) s2 += hid[k] * fc2w[k * NCLS + t];
        o10[t] = s2;
    }
    __syncthreads();
    if (t == 0) {
        float mx = -INFINITY;
        for (int c = 0; c < NCLS; ++c) mx = fmaxf(mx, o10[c]);
        float se = 0.f;
        for (int c = 0; c < NCLS; ++c) se += __expf(o10[c] - mx);
        float lse = mx + logf(se);
        for (int c = 0; c < NCLS; ++c) out[g * NCLS + c] = o10[c] - lse;
    }
}

extern "C" void kernel_launch(void* const* d_in, const int* in_sizes, int n_in,
                              void* d_out, int out_size, void* d_ws, size_t ws_size,
                              hipStream_t stream) {
    (void)n_in; (void)out_size; (void)ws_size;
    const float* x        = (const float*)d_in[0];
    const int*   ei       = (const int*)d_in[1];
    const int*   batch    = (const int*)d_in[2];
    const float* W1       = (const float*)d_in[3];
    const float* att_src1 = (const float*)d_in[4];
    const float* att_dst1 = (const float*)d_in[5];
    const float* b1       = (const float*)d_in[6];
    const float* W2       = (const float*)d_in[7];
    const float* att_src2 = (const float*)d_in[8];
    const float* att_dst2 = (const float*)d_in[9];
    const float* b2       = (const float*)d_in[10];
    const float* fc1w     = (const float*)d_in[11];
    const float* fc1b     = (const float*)d_in[12];
    const float* fc2w     = (const float*)d_in[13];
    const float* fc2b     = (const float*)d_in[14];

    const int N = in_sizes[2];
    const int E = in_sizes[1] / 2;
    const int tot = 2 * E;

    char* base = (char*)d_ws;
    size_t off = 0;
    auto alloc = [&](size_t bytes) -> void* {
        void* p = base + off;
        off = (off + bytes + 255) & ~(size_t)255;
        return p;
    };
    int*   ofs    = (int*)alloc((size_t)(N + 1) * 4);
    int*   cursor = (int*)alloc((size_t)N * 4);
    int*   esrc   = (int*)alloc((size_t)tot * 4);
    float* as1    = (float*)alloc((size_t)N * HEADS * 4);
    float* ad1    = (float*)alloc((size_t)N * HEADS * 4);
    float* as2    = (float*)alloc((size_t)N * 4);
    float* ad2    = (float*)alloc((size_t)N * 4);
    unsigned short* xb   = (unsigned short*)alloc((size_t)N * FDIM * 2);
    unsigned short* W1t  = (unsigned short*)alloc((size_t)512 * 128 * 2);
    unsigned short* W2t  = (unsigned short*)alloc((size_t)256 * 512 * 2);
    unsigned short* h1b  = (unsigned short*)alloc((size_t)N * 512 * 2);
    unsigned short* ho1b = (unsigned short*)alloc((size_t)N * 512 * 2);
    unsigned short* h2b  = (unsigned short*)alloc((size_t)N * 256 * 2);
    float* ho2    = (float*)alloc((size_t)N * 256 * 4);
    float* gpool  = (float*)alloc((size_t)NGRAPH * C2DIM * 4);

    // CSR build
    hipMemsetAsync(cursor, 0, (size_t)N * 4, stream);
    hist_kernel<<<(tot + 255) / 256, 256, 0, stream>>>(ei, E, cursor);
    scan_kernel<<<1, 1024, 0, stream>>>(cursor, ofs, N);
    scatter_kernel<<<(tot + 255) / 256, 256, 0, stream>>>(ei, E, cursor, esrc);

    // bf16 conversions
    cvt_kernel<<<(N * FDIM / 4 + 255) / 256, 256, 0, stream>>>(x, xb, N * FDIM / 4);
    tconv_kernel<<<dim3(512 / 32, 128 / 32), dim3(32, 8), 0, stream>>>(W1, W1t, 128, 512);
    tconv_kernel<<<dim3(256 / 32, 512 / 32), dim3(32, 8), 0, stream>>>(W2, W2t, 512, 256);

    // Layer 1: h1 = x @ W1  (M=N, N=512, K=128)
    bgemm_kernel<<<dim3(512 / 128, (N + 127) / 128), 256, 0, stream>>>(xb, W1t, h1b, N, 512, 128);
    att1_kernel<<<(N + 3) / 4, 256, 0, stream>>>(h1b, att_src1, att_dst1, as1, ad1, N);
    edge_agg1_kernel<<<(N + 3) / 4, 256, 0, stream>>>(h1b, (const float4*)as1, (const float4*)ad1,
                                                      ofs, esrc, b1, ho1b, N);

    // Layer 2: h2 = ho1 @ W2  (M=N, N=256, K=512)
    bgemm_kernel<<<dim3(256 / 128, (N + 127) / 128), 256, 0, stream>>>(ho1b, W2t, h2b, N, 256, 512);
    att2_kernel<<<(N + 3) / 4, 256, 0, stream>>>(h2b, att_src2, att_dst2, as2, ad2, N);
    edge_agg2_kernel<<<(N + 3) / 4, 256, 0, stream>>>(h2b, as2, ad2, ofs, esrc, b2, ho2, N);

    // Pool + head
    pool_kernel<<<NGRAPH, 256, 0, stream>>>(ho2, batch, N, gpool);
    head_kernel<<<NGRAPH, 64, 0, stream>>>(gpool, fc1w, fc1b, fc2w, fc2b, (float*)d_out);
}

// Round 4
// 308.388 us; speedup vs baseline: 1.7128x; 1.1163x over previous
//
#include <hip/hip_runtime.h>
#include <math.h>

// Problem constants (reference: N=20000, E=160000, F=128, H=4, C1=128, C2=256, G=64, NCLS=10)
#define FDIM 128
#define HEADS 4
#define C1DIM 128
#define C2DIM 256
#define NGRAPH 64
#define NCLS 10
#define PCHUNK 8

typedef __attribute__((ext_vector_type(8))) short short8;   // 8 bf16 (4 VGPRs)
typedef __attribute__((ext_vector_type(4))) float float4v;  // 4 fp32 acc

__device__ __forceinline__ unsigned short f2bf(float f) {
    unsigned u = __builtin_bit_cast(unsigned, f);
    unsigned r = (u + 0x7FFFu + ((u >> 16) & 1u)) >> 16;   // RNE
    return (unsigned short)r;
}
__device__ __forceinline__ float bflo(int u) { return __builtin_bit_cast(float, (unsigned)u << 16); }
__device__ __forceinline__ float bfhi(int u) { return __builtin_bit_cast(float, (unsigned)u & 0xffff0000u); }
__device__ __forceinline__ float lrelu(float x) { return x > 0.f ? x : 0.2f * x; }

// ---------------- CSR build ----------------
__global__ void hist_kernel(const int* __restrict__ ei, int E, int* __restrict__ counts) {
    int i = blockIdx.x * blockDim.x + threadIdx.x;
    if (i >= 2 * E) return;
    int dst = (i < E) ? ei[E + i] : ei[i - E];
    atomicAdd(&counts[dst], 1);
}

__global__ __launch_bounds__(1024) void scan_kernel(int* __restrict__ counts_cursor,
                                                    int* __restrict__ ofs, int N) {
    __shared__ int part[1024];
    int t = threadIdx.x;
    int chunk = (N + 1023) / 1024;
    int b = t * chunk;
    int e = b + chunk; if (e > N) e = N;
    int s = 0;
    for (int i = b; i < e; ++i) s += counts_cursor[i];
    part[t] = s;
    __syncthreads();
    for (int o = 1; o < 1024; o <<= 1) {
        int v = (t >= o) ? part[t - o] : 0;
        __syncthreads();
        part[t] += v;
        __syncthreads();
    }
    int run = part[t] - s;
    for (int i = b; i < e; ++i) {
        int c = counts_cursor[i];
        ofs[i] = run;
        counts_cursor[i] = run;
        run += c;
    }
    if (t == 1023) ofs[N] = part[1023];
}

__global__ void scatter_kernel(const int* __restrict__ ei, int E,
                               int* __restrict__ cursor, int* __restrict__ esrc) {
    int i = blockIdx.x * blockDim.x + threadIdx.x;
    if (i >= 2 * E) return;
    int src = ei[i];
    int dst = (i < E) ? ei[E + i] : ei[i - E];
    int pos = atomicAdd(&cursor[dst], 1);
    esrc[pos] = src;
}

// ---------------- fp32 -> bf16 conversions ----------------
__global__ void cvt_kernel(const float* __restrict__ src, unsigned short* __restrict__ dst, int n4) {
    int i = blockIdx.x * blockDim.x + threadIdx.x;
    if (i >= n4) return;
    float4 v = ((const float4*)src)[i];
    ushort4 o;
    o.x = f2bf(v.x); o.y = f2bf(v.y); o.z = f2bf(v.z); o.w = f2bf(v.w);
    ((ushort4*)dst)[i] = o;
}

// Transpose-convert weights: W[K,N] fp32 -> Wt[N,K] bf16. Grid (N/32, K/32), block (32,8).
__global__ void tconv_kernel(const float* __restrict__ W, unsigned short* __restrict__ Wt,
                             int K, int N_) {
    __shared__ float tile[32][33];
    int bx = blockIdx.x * 32;
    int by = blockIdx.y * 32;
    int tx = threadIdx.x, ty = threadIdx.y;
    #pragma unroll
    for (int r = 0; r < 32; r += 8)
        tile[ty + r][tx] = W[(size_t)(by + ty + r) * N_ + bx + tx];
    __syncthreads();
    #pragma unroll
    for (int r = 0; r < 32; r += 8)
        Wt[(size_t)(bx + ty + r) * K + by + tx] = f2bf(tile[tx][ty + r]);
}

// ---------------- bf16 MFMA GEMM: C[M,N] = A[M,K] @ Bt[N,K]^T, bf16 out ----------------
__global__ __launch_bounds__(256) void bgemm_kernel(
        const unsigned short* __restrict__ A,   // [M,K] bf16
        const unsigned short* __restrict__ Bt,  // [N,K] bf16
        unsigned short* __restrict__ C,         // [M,N] bf16
        int M, int N_, int K) {
    __shared__ unsigned short As[128 * 32];
    __shared__ unsigned short Bs[128 * 32];
    const int t = threadIdx.x;
    const int lane = t & 63;
    const int wave = t >> 6;
    const int row0 = blockIdx.y * 128, col0 = blockIdx.x * 128;
    const int wr = (wave >> 1) * 64, wc = (wave & 1) * 64;
    float4v acc[4][4] = {};
    for (int k0 = 0; k0 < K; k0 += 32) {
        #pragma unroll
        for (int c = 0; c < 2; ++c) {
            int i = c * 256 + t;
            int gr = row0 + (i >> 2); if (gr >= M) gr = M - 1;
            const unsigned short* gp = A + (size_t)gr * K + k0 + ((i & 3) << 3);
            __builtin_amdgcn_global_load_lds(
                (const __attribute__((address_space(1))) unsigned int*)gp,
                (__attribute__((address_space(3))) unsigned int*)&As[i * 8], 16, 0, 0);
        }
        #pragma unroll
        for (int c = 0; c < 2; ++c) {
            int i = c * 256 + t;
            int gn = col0 + (i >> 2);
            const unsigned short* gp = Bt + (size_t)gn * K + k0 + ((i & 3) << 3);
            __builtin_amdgcn_global_load_lds(
                (const __attribute__((address_space(1))) unsigned int*)gp,
                (__attribute__((address_space(3))) unsigned int*)&Bs[i * 8], 16, 0, 0);
        }
        __syncthreads();
        short8 af[4], bfr[4];
        #pragma unroll
        for (int i = 0; i < 4; ++i)
            af[i] = *(const short8*)&As[(wr + i * 16 + (lane & 15)) * 32 + (lane >> 4) * 8];
        #pragma unroll
        for (int j = 0; j < 4; ++j)
            bfr[j] = *(const short8*)&Bs[(wc + j * 16 + (lane & 15)) * 32 + (lane >> 4) * 8];
        #pragma unroll
        for (int i = 0; i < 4; ++i)
            #pragma unroll
            for (int j = 0; j < 4; ++j)
                acc[i][j] = __builtin_amdgcn_mfma_f32_16x16x32_bf16(af[i], bfr[j], acc[i][j], 0, 0, 0);
        __syncthreads();
    }
    #pragma unroll
    for (int i = 0; i < 4; ++i) {
        int rbase = row0 + wr + i * 16 + (lane >> 4) * 4;
        #pragma unroll
        for (int j = 0; j < 4; ++j) {
            int cc = col0 + wc + j * 16 + (lane & 15);
            #pragma unroll
            for (int p = 0; p < 4; ++p) {
                int r = rbase + p;
                if (r < M) C[(size_t)r * N_ + cc] = f2bf(acc[i][j][p]);
            }
        }
    }
}

// ---------------- attention scalars (bf16 inputs) ----------------
__global__ __launch_bounds__(256) void att1_kernel(const unsigned short* __restrict__ h1b,
                                                   const float* __restrict__ att_src,
                                                   const float* __restrict__ att_dst,
                                                   float* __restrict__ as1,
                                                   float* __restrict__ ad1, int N) {
    int wave = threadIdx.x >> 6, lane = threadIdx.x & 63;
    int node = blockIdx.x * 4 + wave;
    if (node >= N) return;
    int c0 = lane * 8;
    int4 r = *(const int4*)&h1b[(size_t)node * 512 + c0];
    float f0 = bflo(r.x), f1 = bfhi(r.x), f2 = bflo(r.y), f3 = bfhi(r.y);
    float f4 = bflo(r.z), f5 = bfhi(r.z), f6 = bflo(r.w), f7 = bfhi(r.w);
    float4 sA = *(const float4*)&att_src[c0], sB = *(const float4*)&att_src[c0 + 4];
    float4 dA = *(const float4*)&att_dst[c0], dB = *(const float4*)&att_dst[c0 + 4];
    float s = f0 * sA.x + f1 * sA.y + f2 * sA.z + f3 * sA.w
            + f4 * sB.x + f5 * sB.y + f6 * sB.z + f7 * sB.w;
    float d = f0 * dA.x + f1 * dA.y + f2 * dA.z + f3 * dA.w
            + f4 * dB.x + f5 * dB.y + f6 * dB.z + f7 * dB.w;
    #pragma unroll
    for (int o = 1; o <= 8; o <<= 1) { s += __shfl_xor(s, o); d += __shfl_xor(d, o); }
    if ((lane & 15) == 0) {
        int hd = lane >> 4;
        as1[node * 4 + hd] = s;
        ad1[node * 4 + hd] = d;
    }
}

__global__ __launch_bounds__(256) void att2_kernel(const unsigned short* __restrict__ h2b,
                                                   const float* __restrict__ att_src,
                                                   const float* __restrict__ att_dst,
                                                   float* __restrict__ as2,
                                                   float* __restrict__ ad2, int N) {
    int wave = threadIdx.x >> 6, lane = threadIdx.x & 63;
    int node = blockIdx.x * 4 + wave;
    if (node >= N) return;
    int c0 = lane * 4;
    int2 r = *(const int2*)&h2b[(size_t)node * 256 + c0];
    float f0 = bflo(r.x), f1 = bfhi(r.x), f2 = bflo(r.y), f3 = bfhi(r.y);
    float4 sv = *(const float4*)&att_src[c0];
    float4 dv = *(const float4*)&att_dst[c0];
    float s = f0 * sv.x + f1 * sv.y + f2 * sv.z + f3 * sv.w;
    float d = f0 * dv.x + f1 * dv.y + f2 * dv.z + f3 * dv.w;
    #pragma unroll
    for (int o = 32; o > 0; o >>= 1) { s += __shfl_xor(s, o); d += __shfl_xor(d, o); }
    if (lane == 0) { as2[node] = s; ad2[node] = d; }
}

// ---------------- edge softmax + aggregate ----------------
__global__ __launch_bounds__(256) void edge_agg1_kernel(
        const unsigned short* __restrict__ h1b,   // [N,512] bf16
        const float4* __restrict__ as14,
        const float4* __restrict__ ad14,
        const int* __restrict__ ofs,
        const int* __restrict__ esrc,
        const float* __restrict__ b1,
        unsigned short* __restrict__ ho1b, int N) {
    __shared__ float wbuf[4][256];
    __shared__ int   sbuf[4][64];
    __shared__ int   degs[4];
    int wave = threadIdx.x >> 6, lane = threadIdx.x & 63;
    int node = blockIdx.x * 4 + wave;
    bool valid = node < N;
    int beg = 0, end = 0;
    if (valid) { beg = ofs[node]; end = ofs[node + 1]; }
    int deg = end - beg;
    if (lane == 0) degs[wave] = deg;
    __syncthreads();
    int maxdeg = max(max(degs[0], degs[1]), max(degs[2], degs[3]));

    float4 adn = make_float4(0.f, 0.f, 0.f, 0.f), asn = adn;
    if (valid) { adn = ad14[node]; asn = as14[node]; }
    float es0 = lrelu(asn.x + adn.x), es1 = lrelu(asn.y + adn.y);
    float es2 = lrelu(asn.z + adn.z), es3 = lrelu(asn.w + adn.w);
    float m0 = es0, m1 = es1, m2 = es2, m3 = es3;
    for (int e = beg + lane; e < end; e += 64) {
        int s = esrc[e];
        float4 a = as14[s];
        m0 = fmaxf(m0, lrelu(a.x + adn.x));
        m1 = fmaxf(m1, lrelu(a.y + adn.y));
        m2 = fmaxf(m2, lrelu(a.z + adn.z));
        m3 = fmaxf(m3, lrelu(a.w + adn.w));
    }
    #pragma unroll
    for (int o = 32; o > 0; o >>= 1) {
        m0 = fmaxf(m0, __shfl_xor(m0, o));
        m1 = fmaxf(m1, __shfl_xor(m1, o));
        m2 = fmaxf(m2, __shfl_xor(m2, o));
        m3 = fmaxf(m3, __shfl_xor(m3, o));
    }
    int hd = lane >> 4;
    int c0 = lane * 8;
    float w0 = __expf(es0 - m0), w1 = __expf(es1 - m1);
    float w2 = __expf(es2 - m2), w3 = __expf(es3 - m3);
    float wsh = hd == 0 ? w0 : hd == 1 ? w1 : hd == 2 ? w2 : w3;

    float acc[8] = {0.f, 0.f, 0.f, 0.f, 0.f, 0.f, 0.f, 0.f};
    if (valid) {
        int4 r = *(const int4*)&h1b[(size_t)node * 512 + c0];
        acc[0] = wsh * bflo(r.x); acc[1] = wsh * bfhi(r.x);
        acc[2] = wsh * bflo(r.y); acc[3] = wsh * bfhi(r.y);
        acc[4] = wsh * bflo(r.z); acc[5] = wsh * bfhi(r.z);
        acc[6] = wsh * bflo(r.w); acc[7] = wsh * bfhi(r.w);
    }
    float d0 = 0.f, d1 = 0.f, d2 = 0.f, d3 = 0.f;
    for (int cb = 0; cb < maxdeg; cb += 64) {
        __syncthreads();
        float4 w = make_float4(0.f, 0.f, 0.f, 0.f);
        int s = 0;
        if (cb + lane < deg) {
            s = esrc[beg + cb + lane];
            float4 a = as14[s];
            w.x = __expf(lrelu(a.x + adn.x) - m0);
            w.y = __expf(lrelu(a.y + adn.y) - m1);
            w.z = __expf(lrelu(a.z + adn.z) - m2);
            w.w = __expf(lrelu(a.w + adn.w) - m3);
            d0 += w.x; d1 += w.y; d2 += w.z; d3 += w.w;
        }
        *(float4*)&wbuf[wave][lane * 4] = w;
        sbuf[wave][lane] = s;
        __syncthreads();
        int jmax = deg - cb; if (jmax > 64) jmax = 64;
        for (int j = 0; j < jmax; ++j) {
            int ss = sbuf[wave][j];
            float wj = wbuf[wave][j * 4 + hd];
            int4 r = *(const int4*)&h1b[(size_t)ss * 512 + c0];
            acc[0] += wj * bflo(r.x); acc[1] += wj * bfhi(r.x);
            acc[2] += wj * bflo(r.y); acc[3] += wj * bfhi(r.y);
            acc[4] += wj * bflo(r.z); acc[5] += wj * bfhi(r.z);
            acc[6] += wj * bflo(r.w); acc[7] += wj * bfhi(r.w);
        }
    }
    #pragma unroll
    for (int o = 32; o > 0; o >>= 1) {
        d0 += __shfl_xor(d0, o); d1 += __shfl_xor(d1, o);
        d2 += __shfl_xor(d2, o); d3 += __shfl_xor(d3, o);
    }
    d0 += w0; d1 += w1; d2 += w2; d3 += w3;
    float dh = hd == 0 ? d0 : hd == 1 ? d1 : hd == 2 ? d2 : d3;
    float inv = 1.f / dh;
    if (valid) {
        float4 bA = *(const float4*)&b1[c0], bB = *(const float4*)&b1[c0 + 4];
        float v0 = fmaxf(acc[0] * inv + bA.x, 0.f), v1 = fmaxf(acc[1] * inv + bA.y, 0.f);
        float v2 = fmaxf(acc[2] * inv + bA.z, 0.f), v3 = fmaxf(acc[3] * inv + bA.w, 0.f);
        float v4 = fmaxf(acc[4] * inv + bB.x, 0.f), v5 = fmaxf(acc[5] * inv + bB.y, 0.f);
        float v6 = fmaxf(acc[6] * inv + bB.z, 0.f), v7 = fmaxf(acc[7] * inv + bB.w, 0.f);
        int4 o;
        o.x = (int)((unsigned)f2bf(v0) | ((unsigned)f2bf(v1) << 16));
        o.y = (int)((unsigned)f2bf(v2) | ((unsigned)f2bf(v3) << 16));
        o.z = (int)((unsigned)f2bf(v4) | ((unsigned)f2bf(v5) << 16));
        o.w = (int)((unsigned)f2bf(v6) | ((unsigned)f2bf(v7) << 16));
        *(int4*)&ho1b[(size_t)node * 512 + c0] = o;
    }
}

__global__ __launch_bounds__(256) void edge_agg2_kernel(
        const unsigned short* __restrict__ h2b,   // [N,256] bf16
        const float* __restrict__ as2,
        const float* __restrict__ ad2,
        const int* __restrict__ ofs,
        const int* __restrict__ esrc,
        const float* __restrict__ b2,
        float* __restrict__ ho2, int N) {
    __shared__ float wbuf[4][64];
    __shared__ int   sbuf[4][64];
    __shared__ int   degs[4];
    int wave = threadIdx.x >> 6, lane = threadIdx.x & 63;
    int node = blockIdx.x * 4 + wave;
    bool valid = node < N;
    int beg = 0, end = 0;
    if (valid) { beg = ofs[node]; end = ofs[node + 1]; }
    int deg = end - beg;
    if (lane == 0) degs[wave] = deg;
    __syncthreads();
    int maxdeg = max(max(degs[0], degs[1]), max(degs[2], degs[3]));

    float adn = valid ? ad2[node] : 0.f;
    float asn = valid ? as2[node] : 0.f;
    float es = lrelu(asn + adn);
    float m = es;
    for (int e = beg + lane; e < end; e += 64) {
        int s = esrc[e];
        m = fmaxf(m, lrelu(as2[s] + adn));
    }
    #pragma unroll
    for (int o = 32; o > 0; o >>= 1) m = fmaxf(m, __shfl_xor(m, o));
    float wself = __expf(es - m);
    int c0 = lane * 4;
    float a0 = 0.f, a1 = 0.f, a2 = 0.f, a3 = 0.f;
    if (valid) {
        int2 r = *(const int2*)&h2b[(size_t)node * 256 + c0];
        a0 = wself * bflo(r.x); a1 = wself * bfhi(r.x);
        a2 = wself * bflo(r.y); a3 = wself * bfhi(r.y);
    }
    float dsum = 0.f;
    for (int cb = 0; cb < maxdeg; cb += 64) {
        __syncthreads();
        float w = 0.f; int s = 0;
        if (cb + lane < deg) {
            s = esrc[beg + cb + lane];
            w = __expf(lrelu(as2[s] + adn) - m);
            dsum += w;
        }
        wbuf[wave][lane] = w;
        sbuf[wave][lane] = s;
        __syncthreads();
        int jmax = deg - cb; if (jmax > 64) jmax = 64;
        for (int j = 0; j < jmax; ++j) {
            int ss = sbuf[wave][j];
            float wj = wbuf[wave][j];
            int2 r = *(const int2*)&h2b[(size_t)ss * 256 + c0];
            a0 += wj * bflo(r.x); a1 += wj * bfhi(r.x);
            a2 += wj * bflo(r.y); a3 += wj * bfhi(r.y);
        }
    }
    #pragma unroll
    for (int o = 32; o > 0; o >>= 1) dsum += __shfl_xor(dsum, o);
    dsum += wself;
    if (valid) {
        float inv = 1.f / dsum;
        float4 bv = *(const float4*)&b2[c0];
        float4 o;
        o.x = a0 * inv + bv.x; o.y = a1 * inv + bv.y;
        o.z = a2 * inv + bv.z; o.w = a3 * inv + bv.w;
        *(float4*)&ho2[(size_t)node * 256 + c0] = o;
    }
}

// ---------------- global max pool, two-stage (batch is sorted) ----------------
// Stage 1: grid (NGRAPH, PCHUNK); each block computes a partial column-max over
// its node sub-range into part[g][c][256].
__global__ __launch_bounds__(256) void pool1_kernel(const float* __restrict__ ho2,
                                                    const int* __restrict__ batch,
                                                    int N, float* __restrict__ part) {
    int g = blockIdx.x, c = blockIdx.y, t = threadIdx.x;
    int lo = 0, hi = N;
    while (lo < hi) { int mid = (lo + hi) >> 1; if (batch[mid] < g) lo = mid + 1; else hi = mid; }
    int start = lo;
    lo = 0; hi = N;
    while (lo < hi) { int mid = (lo + hi) >> 1; if (batch[mid] < g + 1) lo = mid + 1; else hi = mid; }
    int end = lo;
    int len = end - start;
    int cb = start + (int)(((long long)len * c) / PCHUNK);
    int ce = start + (int)(((long long)len * (c + 1)) / PCHUNK);
    float m = -INFINITY;
    for (int n = cb; n < ce; ++n) m = fmaxf(m, ho2[(size_t)n * 256 + t]);
    part[((size_t)g * PCHUNK + c) * 256 + t] = m;
}

// Stage 2: reduce the PCHUNK partials per graph.
__global__ __launch_bounds__(256) void pool2_kernel(const float* __restrict__ part,
                                                    float* __restrict__ gout) {
    int g = blockIdx.x, t = threadIdx.x;
    float m = -INFINITY;
    #pragma unroll
    for (int c = 0; c < PCHUNK; ++c)
        m = fmaxf(m, part[((size_t)g * PCHUNK + c) * 256 + t]);
    gout[g * 256 + t] = m;
}

// ---------------- FC head + log_softmax ----------------
__global__ __launch_bounds__(64) void head_kernel(const float* __restrict__ gp,
                                                  const float* __restrict__ fc1w,
                                                  const float* __restrict__ fc1b,
                                                  const float* __restrict__ fc2w,
                                                  const float* __restrict__ fc2b,
                                                  float* __restrict__ out) {
    __shared__ float gr[256];
    __shared__ float hid[64];
    __shared__ float o10[NCLS];
    int g = blockIdx.x, t = threadIdx.x;
    for (int i = t; i < 256; i += 64) gr[i] = gp[g * 256 + i];
    __syncthreads();
    float s = fc1b[t];
    for (int k = 0; k < 256; ++k) s += gr[k] * fc1w[k * 64 + t];
    hid[t] = s > 0.f ? s : 0.f;
    __syncthreads();
    if (t < NCLS) {
        float s2 = fc2b[t];
        for (int k = 0; k < 64; ++k) s2 += hid[k] * fc2w[k * NCLS + t];
        o10[t] = s2;
    }
    __syncthreads();
    if (t == 0) {
        float mx = -INFINITY;
        for (int c = 0; c < NCLS; ++c) mx = fmaxf(mx, o10[c]);
        float se = 0.f;
        for (int c = 0; c < NCLS; ++c) se += __expf(o10[c] - mx);
        float lse = mx + logf(se);
        for (int c = 0; c < NCLS; ++c) out[g * NCLS + c] = o10[c] - lse;
    }
}

extern "C" void kernel_launch(void* const* d_in, const int* in_sizes, int n_in,
                              void* d_out, int out_size, void* d_ws, size_t ws_size,
                              hipStream_t stream) {
    (void)n_in; (void)out_size; (void)ws_size;
    const float* x        = (const float*)d_in[0];
    const int*   ei       = (const int*)d_in[1];
    const int*   batch    = (const int*)d_in[2];
    const float* W1       = (const float*)d_in[3];
    const float* att_src1 = (const float*)d_in[4];
    const float* att_dst1 = (const float*)d_in[5];
    const float* b1       = (const float*)d_in[6];
    const float* W2       = (const float*)d_in[7];
    const float* att_src2 = (const float*)d_in[8];
    const float* att_dst2 = (const float*)d_in[9];
    const float* b2       = (const float*)d_in[10];
    const float* fc1w     = (const float*)d_in[11];
    const float* fc1b     = (const float*)d_in[12];
    const float* fc2w     = (const float*)d_in[13];
    const float* fc2b     = (const float*)d_in[14];

    const int N = in_sizes[2];
    const int E = in_sizes[1] / 2;
    const int tot = 2 * E;

    char* base = (char*)d_ws;
    size_t off = 0;
    auto alloc = [&](size_t bytes) -> void* {
        void* p = base + off;
        off = (off + bytes + 255) & ~(size_t)255;
        return p;
    };
    int*   ofs    = (int*)alloc((size_t)(N + 1) * 4);
    int*   cursor = (int*)alloc((size_t)N * 4);
    int*   esrc   = (int*)alloc((size_t)tot * 4);
    float* as1    = (float*)alloc((size_t)N * HEADS * 4);
    float* ad1    = (float*)alloc((size_t)N * HEADS * 4);
    float* as2    = (float*)alloc((size_t)N * 4);
    float* ad2    = (float*)alloc((size_t)N * 4);
    unsigned short* xb   = (unsigned short*)alloc((size_t)N * FDIM * 2);
    unsigned short* W1t  = (unsigned short*)alloc((size_t)512 * 128 * 2);
    unsigned short* W2t  = (unsigned short*)alloc((size_t)256 * 512 * 2);
    unsigned short* h1b  = (unsigned short*)alloc((size_t)N * 512 * 2);
    unsigned short* ho1b = (unsigned short*)alloc((size_t)N * 512 * 2);
    unsigned short* h2b  = (unsigned short*)alloc((size_t)N * 256 * 2);
    float* ho2    = (float*)alloc((size_t)N * 256 * 4);
    float* ppart  = (float*)alloc((size_t)NGRAPH * PCHUNK * 256 * 4);
    float* gpool  = (float*)alloc((size_t)NGRAPH * C2DIM * 4);

    // CSR build
    hipMemsetAsync(cursor, 0, (size_t)N * 4, stream);
    hist_kernel<<<(tot + 255) / 256, 256, 0, stream>>>(ei, E, cursor);
    scan_kernel<<<1, 1024, 0, stream>>>(cursor, ofs, N);
    scatter_kernel<<<(tot + 255) / 256, 256, 0, stream>>>(ei, E, cursor, esrc);

    // bf16 conversions
    cvt_kernel<<<(N * FDIM / 4 + 255) / 256, 256, 0, stream>>>(x, xb, N * FDIM / 4);
    tconv_kernel<<<dim3(512 / 32, 128 / 32), dim3(32, 8), 0, stream>>>(W1, W1t, 128, 512);
    tconv_kernel<<<dim3(256 / 32, 512 / 32), dim3(32, 8), 0, stream>>>(W2, W2t, 512, 256);

    // Layer 1: h1 = x @ W1  (M=N, N=512, K=128)
    bgemm_kernel<<<dim3(512 / 128, (N + 127) / 128), 256, 0, stream>>>(xb, W1t, h1b, N, 512, 128);
    att1_kernel<<<(N + 3) / 4, 256, 0, stream>>>(h1b, att_src1, att_dst1, as1, ad1, N);
    edge_agg1_kernel<<<(N + 3) / 4, 256, 0, stream>>>(h1b, (const float4*)as1, (const float4*)ad1,
                                                      ofs, esrc, b1, ho1b, N);

    // Layer 2: h2 = ho1 @ W2  (M=N, N=256, K=512)
    bgemm_kernel<<<dim3(256 / 128, (N + 127) / 128), 256, 0, stream>>>(ho1b, W2t, h2b, N, 256, 512);
    att2_kernel<<<(N + 3) / 4, 256, 0, stream>>>(h2b, att_src2, att_dst2, as2, ad2, N);
    edge_agg2_kernel<<<(N + 3) / 4, 256, 0, stream>>>(h2b, as2, ad2, ofs, esrc, b2, ho2, N);

    // Pool (two-stage) + head
    pool1_kernel<<<dim3(NGRAPH, PCHUNK), 256, 0, stream>>>(ho2, batch, N, ppart);
    pool2_kernel<<<NGRAPH, 256, 0, stream>>>(ppart, gpool);
    head_kernel<<<NGRAPH, 64, 0, stream>>>(gpool, fc1w, fc1b, fc2w, fc2b, (float*)d_out);
}

// Round 5
// 307.099 us; speedup vs baseline: 1.7200x; 1.0042x over previous
//
#include <hip/hip_runtime.h>
#include <math.h>

// Problem constants (reference: N=20000, E=160000, F=128, H=4, C1=128, C2=256, G=64, NCLS=10)
#define FDIM 128
#define HEADS 4
#define C1DIM 128
#define C2DIM 256
#define NGRAPH 64
#define NCLS 10
#define PCHUNK 8

typedef __attribute__((ext_vector_type(8))) short short8;   // 8 bf16 (4 VGPRs)
typedef __attribute__((ext_vector_type(4))) float float4v;  // 4 fp32 acc

__device__ __forceinline__ unsigned short f2bf(float f) {
    unsigned u = __builtin_bit_cast(unsigned, f);
    unsigned r = (u + 0x7FFFu + ((u >> 16) & 1u)) >> 16;   // RNE
    return (unsigned short)r;
}
__device__ __forceinline__ float bflo(int u) { return __builtin_bit_cast(float, (unsigned)u << 16); }
__device__ __forceinline__ float bfhi(int u) { return __builtin_bit_cast(float, (unsigned)u & 0xffff0000u); }
__device__ __forceinline__ float lrelu(float x) { return x > 0.f ? x : 0.2f * x; }

// ---------------- CSR build ----------------
__global__ void hist_kernel(const int* __restrict__ ei, int E, int* __restrict__ counts) {
    int i = blockIdx.x * blockDim.x + threadIdx.x;
    if (i >= 2 * E) return;
    int dst = (i < E) ? ei[E + i] : ei[i - E];
    atomicAdd(&counts[dst], 1);
}

__global__ __launch_bounds__(1024) void scan_kernel(int* __restrict__ counts_cursor,
                                                    int* __restrict__ ofs, int N) {
    __shared__ int part[1024];
    int t = threadIdx.x;
    int chunk = (N + 1023) / 1024;
    int b = t * chunk;
    int e = b + chunk; if (e > N) e = N;
    int s = 0;
    for (int i = b; i < e; ++i) s += counts_cursor[i];
    part[t] = s;
    __syncthreads();
    for (int o = 1; o < 1024; o <<= 1) {
        int v = (t >= o) ? part[t - o] : 0;
        __syncthreads();
        part[t] += v;
        __syncthreads();
    }
    int run = part[t] - s;
    for (int i = b; i < e; ++i) {
        int c = counts_cursor[i];
        ofs[i] = run;
        counts_cursor[i] = run;
        run += c;
    }
    if (t == 1023) ofs[N] = part[1023];
}

__global__ void scatter_kernel(const int* __restrict__ ei, int E,
                               int* __restrict__ cursor, int* __restrict__ esrc,
                               int* __restrict__ edst) {
    int i = blockIdx.x * blockDim.x + threadIdx.x;
    if (i >= 2 * E) return;
    int src = ei[i];
    int dst = (i < E) ? ei[E + i] : ei[i - E];
    int pos = atomicAdd(&cursor[dst], 1);
    esrc[pos] = src;
    edst[pos] = dst;
}

// ---------------- fp32 -> bf16 conversions ----------------
__global__ void cvt_kernel(const float* __restrict__ src, unsigned short* __restrict__ dst, int n4) {
    int i = blockIdx.x * blockDim.x + threadIdx.x;
    if (i >= n4) return;
    float4 v = ((const float4*)src)[i];
    ushort4 o;
    o.x = f2bf(v.x); o.y = f2bf(v.y); o.z = f2bf(v.z); o.w = f2bf(v.w);
    ((ushort4*)dst)[i] = o;
}

// Transpose-convert weights: W[K,N] fp32 -> Wt[N,K] bf16. Grid (N/32, K/32), block (32,8).
__global__ void tconv_kernel(const float* __restrict__ W, unsigned short* __restrict__ Wt,
                             int K, int N_) {
    __shared__ float tile[32][33];
    int bx = blockIdx.x * 32;
    int by = blockIdx.y * 32;
    int tx = threadIdx.x, ty = threadIdx.y;
    #pragma unroll
    for (int r = 0; r < 32; r += 8)
        tile[ty + r][tx] = W[(size_t)(by + ty + r) * N_ + bx + tx];
    __syncthreads();
    #pragma unroll
    for (int r = 0; r < 32; r += 8)
        Wt[(size_t)(bx + ty + r) * K + by + tx] = f2bf(tile[tx][ty + r]);
}

// ---------------- bf16 MFMA GEMM: C[M,N] = A[M,K] @ Bt[N,K]^T, bf16 out ----------------
__global__ __launch_bounds__(256) void bgemm_kernel(
        const unsigned short* __restrict__ A,   // [M,K] bf16
        const unsigned short* __restrict__ Bt,  // [N,K] bf16
        unsigned short* __restrict__ C,         // [M,N] bf16
        int M, int N_, int K) {
    __shared__ unsigned short As[128 * 32];
    __shared__ unsigned short Bs[128 * 32];
    const int t = threadIdx.x;
    const int lane = t & 63;
    const int wave = t >> 6;
    const int row0 = blockIdx.y * 128, col0 = blockIdx.x * 128;
    const int wr = (wave >> 1) * 64, wc = (wave & 1) * 64;
    float4v acc[4][4] = {};
    for (int k0 = 0; k0 < K; k0 += 32) {
        #pragma unroll
        for (int c = 0; c < 2; ++c) {
            int i = c * 256 + t;
            int gr = row0 + (i >> 2); if (gr >= M) gr = M - 1;
            const unsigned short* gp = A + (size_t)gr * K + k0 + ((i & 3) << 3);
            __builtin_amdgcn_global_load_lds(
                (const __attribute__((address_space(1))) unsigned int*)gp,
                (__attribute__((address_space(3))) unsigned int*)&As[i * 8], 16, 0, 0);
        }
        #pragma unroll
        for (int c = 0; c < 2; ++c) {
            int i = c * 256 + t;
            int gn = col0 + (i >> 2);
            const unsigned short* gp = Bt + (size_t)gn * K + k0 + ((i & 3) << 3);
            __builtin_amdgcn_global_load_lds(
                (const __attribute__((address_space(1))) unsigned int*)gp,
                (__attribute__((address_space(3))) unsigned int*)&Bs[i * 8], 16, 0, 0);
        }
        __syncthreads();
        short8 af[4], bfr[4];
        #pragma unroll
        for (int i = 0; i < 4; ++i)
            af[i] = *(const short8*)&As[(wr + i * 16 + (lane & 15)) * 32 + (lane >> 4) * 8];
        #pragma unroll
        for (int j = 0; j < 4; ++j)
            bfr[j] = *(const short8*)&Bs[(wc + j * 16 + (lane & 15)) * 32 + (lane >> 4) * 8];
        #pragma unroll
        for (int i = 0; i < 4; ++i)
            #pragma unroll
            for (int j = 0; j < 4; ++j)
                acc[i][j] = __builtin_amdgcn_mfma_f32_16x16x32_bf16(af[i], bfr[j], acc[i][j], 0, 0, 0);
        __syncthreads();
    }
    #pragma unroll
    for (int i = 0; i < 4; ++i) {
        int rbase = row0 + wr + i * 16 + (lane >> 4) * 4;
        #pragma unroll
        for (int j = 0; j < 4; ++j) {
            int cc = col0 + wc + j * 16 + (lane & 15);
            #pragma unroll
            for (int p = 0; p < 4; ++p) {
                int r = rbase + p;
                if (r < M) C[(size_t)r * N_ + cc] = f2bf(acc[i][j][p]);
            }
        }
    }
}

// ---------------- attention scalars (bf16 inputs) ----------------
__global__ __launch_bounds__(256) void att1_kernel(const unsigned short* __restrict__ h1b,
                                                   const float* __restrict__ att_src,
                                                   const float* __restrict__ att_dst,
                                                   float* __restrict__ as1,
                                                   float* __restrict__ ad1, int N) {
    int wave = threadIdx.x >> 6, lane = threadIdx.x & 63;
    int node = blockIdx.x * 4 + wave;
    if (node >= N) return;
    int c0 = lane * 8;
    int4 r = *(const int4*)&h1b[(size_t)node * 512 + c0];
    float f0 = bflo(r.x), f1 = bfhi(r.x), f2 = bflo(r.y), f3 = bfhi(r.y);
    float f4 = bflo(r.z), f5 = bfhi(r.z), f6 = bflo(r.w), f7 = bfhi(r.w);
    float4 sA = *(const float4*)&att_src[c0], sB = *(const float4*)&att_src[c0 + 4];
    float4 dA = *(const float4*)&att_dst[c0], dB = *(const float4*)&att_dst[c0 + 4];
    float s = f0 * sA.x + f1 * sA.y + f2 * sA.z + f3 * sA.w
            + f4 * sB.x + f5 * sB.y + f6 * sB.z + f7 * sB.w;
    float d = f0 * dA.x + f1 * dA.y + f2 * dA.z + f3 * dA.w
            + f4 * dB.x + f5 * dB.y + f6 * dB.z + f7 * dB.w;
    #pragma unroll
    for (int o = 1; o <= 8; o <<= 1) { s += __shfl_xor(s, o); d += __shfl_xor(d, o); }
    if ((lane & 15) == 0) {
        int hd = lane >> 4;
        as1[node * 4 + hd] = s;
        ad1[node * 4 + hd] = d;
    }
}

__global__ __launch_bounds__(256) void att2_kernel(const unsigned short* __restrict__ h2b,
                                                   const float* __restrict__ att_src,
                                                   const float* __restrict__ att_dst,
                                                   float* __restrict__ as2,
                                                   float* __restrict__ ad2, int N) {
    int wave = threadIdx.x >> 6, lane = threadIdx.x & 63;
    int node = blockIdx.x * 4 + wave;
    if (node >= N) return;
    int c0 = lane * 4;
    int2 r = *(const int2*)&h2b[(size_t)node * 256 + c0];
    float f0 = bflo(r.x), f1 = bfhi(r.x), f2 = bflo(r.y), f3 = bfhi(r.y);
    float4 sv = *(const float4*)&att_src[c0];
    float4 dv = *(const float4*)&att_dst[c0];
    float s = f0 * sv.x + f1 * sv.y + f2 * sv.z + f3 * sv.w;
    float d = f0 * dv.x + f1 * dv.y + f2 * dv.z + f3 * dv.w;
    #pragma unroll
    for (int o = 32; o > 0; o >>= 1) { s += __shfl_xor(s, o); d += __shfl_xor(d, o); }
    if (lane == 0) { as2[node] = s; ad2[node] = d; }
}

// ---------------- edge-parallel attention-weight precompute ----------------
// No max-subtraction: scores are bounded (|score| < ~5), exp ratios identical.
__global__ void wcalc1_kernel(const float4* __restrict__ as14, const float4* __restrict__ ad14,
                              const int* __restrict__ esrc, const int* __restrict__ edst,
                              float4* __restrict__ wexp4, int tot) {
    int e = blockIdx.x * blockDim.x + threadIdx.x;
    if (e >= tot) return;
    float4 a = as14[esrc[e]];
    float4 b = ad14[edst[e]];
    float4 w;
    w.x = __expf(lrelu(a.x + b.x));
    w.y = __expf(lrelu(a.y + b.y));
    w.z = __expf(lrelu(a.z + b.z));
    w.w = __expf(lrelu(a.w + b.w));
    wexp4[e] = w;
}

__global__ void wcalc2_kernel(const float* __restrict__ as2, const float* __restrict__ ad2,
                              const int* __restrict__ esrc, const int* __restrict__ edst,
                              float* __restrict__ wexp, int tot) {
    int e = blockIdx.x * blockDim.x + threadIdx.x;
    if (e >= tot) return;
    wexp[e] = __expf(lrelu(as2[esrc[e]] + ad2[edst[e]]));
}

// ---------------- edge aggregate (pure gather, no LDS, no barriers) ----------------
// Layer 1: one wave per node; lane = 8 channels of 512; head = lane>>4.
__global__ __launch_bounds__(256) void edge_agg1_kernel(
        const unsigned short* __restrict__ h1b,   // [N,512] bf16
        const float4* __restrict__ as14,
        const float4* __restrict__ ad14,
        const int* __restrict__ ofs,
        const int* __restrict__ esrc,
        const float* __restrict__ wexp,           // [tot*4]
        const float* __restrict__ b1,
        unsigned short* __restrict__ ho1b, int N) {
    int wave = threadIdx.x >> 6, lane = threadIdx.x & 63;
    int node = blockIdx.x * 4 + wave;
    if (node >= N) return;
    int beg = ofs[node], end = ofs[node + 1];
    float4 asn = as14[node], adn = ad14[node];
    float w0 = __expf(lrelu(asn.x + adn.x));
    float w1 = __expf(lrelu(asn.y + adn.y));
    float w2 = __expf(lrelu(asn.z + adn.z));
    float w3 = __expf(lrelu(asn.w + adn.w));
    // denominator: coalesced linear sum of wexp4 over the edge range
    float d0 = 0.f, d1 = 0.f, d2 = 0.f, d3 = 0.f;
    for (int e = beg + lane; e < end; e += 64) {
        float4 w = ((const float4*)wexp)[e];
        d0 += w.x; d1 += w.y; d2 += w.z; d3 += w.w;
    }
    #pragma unroll
    for (int o = 32; o > 0; o >>= 1) {
        d0 += __shfl_xor(d0, o); d1 += __shfl_xor(d1, o);
        d2 += __shfl_xor(d2, o); d3 += __shfl_xor(d3, o);
    }
    d0 += w0; d1 += w1; d2 += w2; d3 += w3;
    int hd = lane >> 4;
    int c0 = lane * 8;
    float wsh = hd == 0 ? w0 : hd == 1 ? w1 : hd == 2 ? w2 : w3;
    float dh  = hd == 0 ? d0 : hd == 1 ? d1 : hd == 2 ? d2 : d3;

    float acc[8];
    {
        int4 r = *(const int4*)&h1b[(size_t)node * 512 + c0];
        acc[0] = wsh * bflo(r.x); acc[1] = wsh * bfhi(r.x);
        acc[2] = wsh * bflo(r.y); acc[3] = wsh * bfhi(r.y);
        acc[4] = wsh * bflo(r.z); acc[5] = wsh * bfhi(r.z);
        acc[6] = wsh * bflo(r.w); acc[7] = wsh * bfhi(r.w);
    }
    int e = beg;
    for (; e + 4 <= end; e += 4) {
        int s0 = esrc[e], s1 = esrc[e + 1], s2 = esrc[e + 2], s3 = esrc[e + 3];
        float u0 = wexp[(size_t)(e + 0) * 4 + hd];
        float u1 = wexp[(size_t)(e + 1) * 4 + hd];
        float u2 = wexp[(size_t)(e + 2) * 4 + hd];
        float u3 = wexp[(size_t)(e + 3) * 4 + hd];
        int4 r0 = *(const int4*)&h1b[(size_t)s0 * 512 + c0];
        int4 r1 = *(const int4*)&h1b[(size_t)s1 * 512 + c0];
        int4 r2 = *(const int4*)&h1b[(size_t)s2 * 512 + c0];
        int4 r3 = *(const int4*)&h1b[(size_t)s3 * 512 + c0];
        acc[0] += u0 * bflo(r0.x); acc[1] += u0 * bfhi(r0.x);
        acc[2] += u0 * bflo(r0.y); acc[3] += u0 * bfhi(r0.y);
        acc[4] += u0 * bflo(r0.z); acc[5] += u0 * bfhi(r0.z);
        acc[6] += u0 * bflo(r0.w); acc[7] += u0 * bfhi(r0.w);
        acc[0] += u1 * bflo(r1.x); acc[1] += u1 * bfhi(r1.x);
        acc[2] += u1 * bflo(r1.y); acc[3] += u1 * bfhi(r1.y);
        acc[4] += u1 * bflo(r1.z); acc[5] += u1 * bfhi(r1.z);
        acc[6] += u1 * bflo(r1.w); acc[7] += u1 * bfhi(r1.w);
        acc[0] += u2 * bflo(r2.x); acc[1] += u2 * bfhi(r2.x);
        acc[2] += u2 * bflo(r2.y); acc[3] += u2 * bfhi(r2.y);
        acc[4] += u2 * bflo(r2.z); acc[5] += u2 * bfhi(r2.z);
        acc[6] += u2 * bflo(r2.w); acc[7] += u2 * bfhi(r2.w);
        acc[0] += u3 * bflo(r3.x); acc[1] += u3 * bfhi(r3.x);
        acc[2] += u3 * bflo(r3.y); acc[3] += u3 * bfhi(r3.y);
        acc[4] += u3 * bflo(r3.z); acc[5] += u3 * bfhi(r3.z);
        acc[6] += u3 * bflo(r3.w); acc[7] += u3 * bfhi(r3.w);
    }
    for (; e < end; ++e) {
        int s = esrc[e];
        float u = wexp[(size_t)e * 4 + hd];
        int4 r = *(const int4*)&h1b[(size_t)s * 512 + c0];
        acc[0] += u * bflo(r.x); acc[1] += u * bfhi(r.x);
        acc[2] += u * bflo(r.y); acc[3] += u * bfhi(r.y);
        acc[4] += u * bflo(r.z); acc[5] += u * bfhi(r.z);
        acc[6] += u * bflo(r.w); acc[7] += u * bfhi(r.w);
    }
    float inv = 1.f / dh;
    float4 bA = *(const float4*)&b1[c0], bB = *(const float4*)&b1[c0 + 4];
    float v0 = fmaxf(acc[0] * inv + bA.x, 0.f), v1 = fmaxf(acc[1] * inv + bA.y, 0.f);
    float v2 = fmaxf(acc[2] * inv + bA.z, 0.f), v3 = fmaxf(acc[3] * inv + bA.w, 0.f);
    float v4 = fmaxf(acc[4] * inv + bB.x, 0.f), v5 = fmaxf(acc[5] * inv + bB.y, 0.f);
    float v6 = fmaxf(acc[6] * inv + bB.z, 0.f), v7 = fmaxf(acc[7] * inv + bB.w, 0.f);
    int4 o;
    o.x = (int)((unsigned)f2bf(v0) | ((unsigned)f2bf(v1) << 16));
    o.y = (int)((unsigned)f2bf(v2) | ((unsigned)f2bf(v3) << 16));
    o.z = (int)((unsigned)f2bf(v4) | ((unsigned)f2bf(v5) << 16));
    o.w = (int)((unsigned)f2bf(v6) | ((unsigned)f2bf(v7) << 16));
    *(int4*)&ho1b[(size_t)node * 512 + c0] = o;
}

// Layer 2: one wave per node, 1 head, lane = 4 channels of 256 (bf16 gather).
__global__ __launch_bounds__(256) void edge_agg2_kernel(
        const unsigned short* __restrict__ h2b,   // [N,256] bf16
        const float* __restrict__ as2,
        const float* __restrict__ ad2,
        const int* __restrict__ ofs,
        const int* __restrict__ esrc,
        const float* __restrict__ wexp,           // [tot]
        const float* __restrict__ b2,
        float* __restrict__ ho2, int N) {
    int wave = threadIdx.x >> 6, lane = threadIdx.x & 63;
    int node = blockIdx.x * 4 + wave;
    if (node >= N) return;
    int beg = ofs[node], end = ofs[node + 1];
    float wself = __expf(lrelu(as2[node] + ad2[node]));
    float dsum = 0.f;
    for (int e = beg + lane; e < end; e += 64) dsum += wexp[e];
    #pragma unroll
    for (int o = 32; o > 0; o >>= 1) dsum += __shfl_xor(dsum, o);
    dsum += wself;
    int c0 = lane * 4;
    float a0, a1, a2, a3;
    {
        int2 r = *(const int2*)&h2b[(size_t)node * 256 + c0];
        a0 = wself * bflo(r.x); a1 = wself * bfhi(r.x);
        a2 = wself * bflo(r.y); a3 = wself * bfhi(r.y);
    }
    int e = beg;
    for (; e + 4 <= end; e += 4) {
        int s0 = esrc[e], s1 = esrc[e + 1], s2 = esrc[e + 2], s3 = esrc[e + 3];
        float u0 = wexp[e], u1 = wexp[e + 1], u2 = wexp[e + 2], u3 = wexp[e + 3];
        int2 r0 = *(const int2*)&h2b[(size_t)s0 * 256 + c0];
        int2 r1 = *(const int2*)&h2b[(size_t)s1 * 256 + c0];
        int2 r2 = *(const int2*)&h2b[(size_t)s2 * 256 + c0];
        int2 r3 = *(const int2*)&h2b[(size_t)s3 * 256 + c0];
        a0 += u0 * bflo(r0.x); a1 += u0 * bfhi(r0.x);
        a2 += u0 * bflo(r0.y); a3 += u0 * bfhi(r0.y);
        a0 += u1 * bflo(r1.x); a1 += u1 * bfhi(r1.x);
        a2 += u1 * bflo(r1.y); a3 += u1 * bfhi(r1.y);
        a0 += u2 * bflo(r2.x); a1 += u2 * bfhi(r2.x);
        a2 += u2 * bflo(r2.y); a3 += u2 * bfhi(r2.y);
        a0 += u3 * bflo(r3.x); a1 += u3 * bfhi(r3.x);
        a2 += u3 * bflo(r3.y); a3 += u3 * bfhi(r3.y);
    }
    for (; e < end; ++e) {
        int s = esrc[e];
        float u = wexp[e];
        int2 r = *(const int2*)&h2b[(size_t)s * 256 + c0];
        a0 += u * bflo(r.x); a1 += u * bfhi(r.x);
        a2 += u * bflo(r.y); a3 += u * bfhi(r.y);
    }
    float inv = 1.f / dsum;
    float4 bv = *(const float4*)&b2[c0];
    float4 o;
    o.x = a0 * inv + bv.x; o.y = a1 * inv + bv.y;
    o.z = a2 * inv + bv.z; o.w = a3 * inv + bv.w;
    *(float4*)&ho2[(size_t)node * 256 + c0] = o;
}

// ---------------- global max pool, two-stage (batch is sorted) ----------------
__global__ __launch_bounds__(256) void pool1_kernel(const float* __restrict__ ho2,
                                                    const int* __restrict__ batch,
                                                    int N, float* __restrict__ part) {
    int g = blockIdx.x, c = blockIdx.y, t = threadIdx.x;
    int lo = 0, hi = N;
    while (lo < hi) { int mid = (lo + hi) >> 1; if (batch[mid] < g) lo = mid + 1; else hi = mid; }
    int start = lo;
    lo = 0; hi = N;
    while (lo < hi) { int mid = (lo + hi) >> 1; if (batch[mid] < g + 1) lo = mid + 1; else hi = mid; }
    int end = lo;
    int len = end - start;
    int cb = start + (int)(((long long)len * c) / PCHUNK);
    int ce = start + (int)(((long long)len * (c + 1)) / PCHUNK);
    float m = -INFINITY;
    for (int n = cb; n < ce; ++n) m = fmaxf(m, ho2[(size_t)n * 256 + t]);
    part[((size_t)g * PCHUNK + c) * 256 + t] = m;
}

__global__ __launch_bounds__(256) void pool2_kernel(const float* __restrict__ part,
                                                    float* __restrict__ gout) {
    int g = blockIdx.x, t = threadIdx.x;
    float m = -INFINITY;
    #pragma unroll
    for (int c = 0; c < PCHUNK; ++c)
        m = fmaxf(m, part[((size_t)g * PCHUNK + c) * 256 + t]);
    gout[g * 256 + t] = m;
}

// ---------------- FC head + log_softmax ----------------
__global__ __launch_bounds__(64) void head_kernel(const float* __restrict__ gp,
                                                  const float* __restrict__ fc1w,
                                                  const float* __restrict__ fc1b,
                                                  const float* __restrict__ fc2w,
                                                  const float* __restrict__ fc2b,
                                                  float* __restrict__ out) {
    __shared__ float gr[256];
    __shared__ float hid[64];
    __shared__ float o10[NCLS];
    int g = blockIdx.x, t = threadIdx.x;
    for (int i = t; i < 256; i += 64) gr[i] = gp[g * 256 + i];
    __syncthreads();
    float s = fc1b[t];
    for (int k = 0; k < 256; ++k) s += gr[k] * fc1w[k * 64 + t];
    hid[t] = s > 0.f ? s : 0.f;
    __syncthreads();
    if (t < NCLS) {
        float s2 = fc2b[t];
        for (int k = 0; k < 64; ++k) s2 += hid[k] * fc2w[k * NCLS + t];
        o10[t] = s2;
    }
    __syncthreads();
    if (t == 0) {
        float mx = -INFINITY;
        for (int c = 0; c < NCLS; ++c) mx = fmaxf(mx, o10[c]);
        float se = 0.f;
        for (int c = 0; c < NCLS; ++c) se += __expf(o10[c] - mx);
        float lse = mx + logf(se);
        for (int c = 0; c < NCLS; ++c) out[g * NCLS + c] = o10[c] - lse;
    }
}

extern "C" void kernel_launch(void* const* d_in, const int* in_sizes, int n_in,
                              void* d_out, int out_size, void* d_ws, size_t ws_size,
                              hipStream_t stream) {
    (void)n_in; (void)out_size; (void)ws_size;
    const float* x        = (const float*)d_in[0];
    const int*   ei       = (const int*)d_in[1];
    const int*   batch    = (const int*)d_in[2];
    const float* W1       = (const float*)d_in[3];
    const float* att_src1 = (const float*)d_in[4];
    const float* att_dst1 = (const float*)d_in[5];
    const float* b1       = (const float*)d_in[6];
    const float* W2       = (const float*)d_in[7];
    const float* att_src2 = (const float*)d_in[8];
    const float* att_dst2 = (const float*)d_in[9];
    const float* b2       = (const float*)d_in[10];
    const float* fc1w     = (const float*)d_in[11];
    const float* fc1b     = (const float*)d_in[12];
    const float* fc2w     = (const float*)d_in[13];
    const float* fc2b     = (const float*)d_in[14];

    const int N = in_sizes[2];
    const int E = in_sizes[1] / 2;
    const int tot = 2 * E;

    char* base = (char*)d_ws;
    size_t off = 0;
    auto alloc = [&](size_t bytes) -> void* {
        void* p = base + off;
        off = (off + bytes + 255) & ~(size_t)255;
        return p;
    };
    int*   ofs    = (int*)alloc((size_t)(N + 1) * 4);
    int*   cursor = (int*)alloc((size_t)N * 4);
    int*   esrc   = (int*)alloc((size_t)tot * 4);
    int*   edst   = (int*)alloc((size_t)tot * 4);
    float* as1    = (float*)alloc((size_t)N * HEADS * 4);
    float* ad1    = (float*)alloc((size_t)N * HEADS * 4);
    float* as2    = (float*)alloc((size_t)N * 4);
    float* ad2    = (float*)alloc((size_t)N * 4);
    float* wexp1  = (float*)alloc((size_t)tot * HEADS * 4);
    float* wexp2  = (float*)alloc((size_t)tot * 4);
    unsigned short* xb   = (unsigned short*)alloc((size_t)N * FDIM * 2);
    unsigned short* W1t  = (unsigned short*)alloc((size_t)512 * 128 * 2);
    unsigned short* W2t  = (unsigned short*)alloc((size_t)256 * 512 * 2);
    unsigned short* h1b  = (unsigned short*)alloc((size_t)N * 512 * 2);
    unsigned short* ho1b = (unsigned short*)alloc((size_t)N * 512 * 2);
    unsigned short* h2b  = (unsigned short*)alloc((size_t)N * 256 * 2);
    float* ho2    = (float*)alloc((size_t)N * 256 * 4);
    float* ppart  = (float*)alloc((size_t)NGRAPH * PCHUNK * 256 * 4);
    float* gpool  = (float*)alloc((size_t)NGRAPH * C2DIM * 4);

    // CSR build
    hipMemsetAsync(cursor, 0, (size_t)N * 4, stream);
    hist_kernel<<<(tot + 255) / 256, 256, 0, stream>>>(ei, E, cursor);
    scan_kernel<<<1, 1024, 0, stream>>>(cursor, ofs, N);
    scatter_kernel<<<(tot + 255) / 256, 256, 0, stream>>>(ei, E, cursor, esrc, edst);

    // bf16 conversions
    cvt_kernel<<<(N * FDIM / 4 + 255) / 256, 256, 0, stream>>>(x, xb, N * FDIM / 4);
    tconv_kernel<<<dim3(512 / 32, 128 / 32), dim3(32, 8), 0, stream>>>(W1, W1t, 128, 512);
    tconv_kernel<<<dim3(256 / 32, 512 / 32), dim3(32, 8), 0, stream>>>(W2, W2t, 512, 256);

    // Layer 1: h1 = x @ W1  (M=N, N=512, K=128)
    bgemm_kernel<<<dim3(512 / 128, (N + 127) / 128), 256, 0, stream>>>(xb, W1t, h1b, N, 512, 128);
    att1_kernel<<<(N + 3) / 4, 256, 0, stream>>>(h1b, att_src1, att_dst1, as1, ad1, N);
    wcalc1_kernel<<<(tot + 255) / 256, 256, 0, stream>>>((const float4*)as1, (const float4*)ad1,
                                                         esrc, edst, (float4*)wexp1, tot);
    edge_agg1_kernel<<<(N + 3) / 4, 256, 0, stream>>>(h1b, (const float4*)as1, (const float4*)ad1,
                                                      ofs, esrc, wexp1, b1, ho1b, N);

    // Layer 2: h2 = ho1 @ W2  (M=N, N=256, K=512)
    bgemm_kernel<<<dim3(256 / 128, (N + 127) / 128), 256, 0, stream>>>(ho1b, W2t, h2b, N, 256, 512);
    att2_kernel<<<(N + 3) / 4, 256, 0, stream>>>(h2b, att_src2, att_dst2, as2, ad2, N);
    wcalc2_kernel<<<(tot + 255) / 256, 256, 0, stream>>>(as2, ad2, esrc, edst, wexp2, tot);
    edge_agg2_kernel<<<(N + 3) / 4, 256, 0, stream>>>(h2b, as2, ad2, ofs, esrc, wexp2, b2, ho2, N);

    // Pool (two-stage) + head
    pool1_kernel<<<dim3(NGRAPH, PCHUNK), 256, 0, stream>>>(ho2, batch, N, ppart);
    pool2_kernel<<<NGRAPH, 256, 0, stream>>>(ppart, gpool);
    head_kernel<<<NGRAPH, 64, 0, stream>>>(gpool, fc1w, fc1b, fc2w, fc2b, (float*)d_out);
}